// Round 2
// baseline (392.794 us; speedup 1.0000x reference)
//
#include <hip/hip_runtime.h>

#define F_ 256
#define S_ 512
#define NH_ 16
#define DQ_ 64
#define CH_ 16

__device__ __forceinline__ float sigmoid_f(float x) { return 1.0f / (1.0f + __expf(-x)); }

template<int CTRL>
__device__ __forceinline__ float dpp_add(float x) {
  int y = __builtin_amdgcn_update_dpp(0, __float_as_int(x), CTRL, 0xf, 0xf, true);
  return x + __int_as_float(y);
}

// butterfly sum over each aligned 16-lane group; result broadcast to all 16 lanes
__device__ __forceinline__ float red16(float x) {
  x = dpp_add<0xB1>(x);   // quad_perm [1,0,3,2]
  x = dpp_add<0x4E>(x);   // quad_perm [2,3,0,1]
  x = dpp_add<0x141>(x);  // row_half_mirror
  x = dpp_add<0x140>(x);  // row_mirror
  return x;
}

// C = act(A @ W + bias); A: MxK row-major, W: KxN row-major.
// BM=BN=64, BK=32, 128 threads, 8x4 acc per thread.
__global__ __launch_bounds__(128) void gemm_f32_k(
    const float* __restrict__ A, const float* __restrict__ W,
    const float* __restrict__ bias, float* __restrict__ C,
    int M, int N, int K, int act)
{
  __shared__ float As[32][68];   // transposed A tile; stride 68 keeps rows 16B-aligned, reads conflict-free
  __shared__ float Bs[32][64];
  const int tid = threadIdx.x;   // 0..127
  const int tx = tid & 15;       // col group (4 cols)
  const int ty = tid >> 4;       // row group (8 rows), 0..7
  const int row0 = blockIdx.y * 64;
  const int col0 = blockIdx.x * 64;
  float acc[8][4];
  #pragma unroll
  for (int i = 0; i < 8; ++i)
    #pragma unroll
    for (int j = 0; j < 4; ++j) acc[i][j] = 0.0f;

  for (int k0 = 0; k0 < K; k0 += 32) {
    #pragma unroll
    for (int p = 0; p < 4; ++p) {           // A: 64x32 = 512 float4 / 128 thr
      const int idx = (p << 7) + tid;       // 0..511
      const int r   = idx >> 3;             // 0..63
      const int kk  = (idx & 7) << 2;       // 0..28
      const float4 av = *(const float4*)&A[(size_t)(row0 + r) * K + k0 + kk];
      As[kk + 0][r] = av.x;
      As[kk + 1][r] = av.y;
      As[kk + 2][r] = av.z;
      As[kk + 3][r] = av.w;
    }
    #pragma unroll
    for (int p = 0; p < 4; ++p) {           // B: 32x64 = 512 float4 / 128 thr
      const int idx = (p << 7) + tid;
      const int r   = idx >> 4;             // 0..31
      const int c4  = (idx & 15) << 2;
      *(float4*)&Bs[r][c4] = *(const float4*)&W[(size_t)(k0 + r) * N + col0 + c4];
    }
    __syncthreads();
    #pragma unroll
    for (int kk = 0; kk < 32; ++kk) {
      const float4 b4 = *(const float4*)&Bs[kk][tx << 2];
      const float4 a0 = *(const float4*)&As[kk][ty << 3];
      const float4 a1 = *(const float4*)&As[kk][(ty << 3) + 4];
      const float a[8] = {a0.x, a0.y, a0.z, a0.w, a1.x, a1.y, a1.z, a1.w};
      const float b[4] = {b4.x, b4.y, b4.z, b4.w};
      #pragma unroll
      for (int i = 0; i < 8; ++i)
        #pragma unroll
        for (int j = 0; j < 4; ++j)
          acc[i][j] += a[i] * b[j];
    }
    __syncthreads();
  }

  #pragma unroll
  for (int i = 0; i < 8; ++i) {
    const int row = row0 + (ty << 3) + i;
    const int col = col0 + (tx << 2);
    float4 r = make_float4(acc[i][0], acc[i][1], acc[i][2], acc[i][3]);
    if (bias) {
      const float4 b = *(const float4*)&bias[col];
      r.x += b.x; r.y += b.y; r.z += b.z; r.w += b.w;
    }
    if (act == 1) {
      r.x *= sigmoid_f(r.x); r.y *= sigmoid_f(r.y);
      r.z *= sigmoid_f(r.z); r.w *= sigmoid_f(r.w);
    }
    *(float4*)&C[(size_t)row * N + col] = r;
  }
}

// in-place row L2-normalize, one wave per 256-float row
__global__ __launch_bounds__(256) void knorm_k(float* __restrict__ k)
{
  const int lane = threadIdx.x & 63;
  const size_t row = ((size_t)blockIdx.x << 2) + (threadIdx.x >> 6);
  const size_t off = row * F_ + ((size_t)lane << 2);
  float4 v = *(float4*)&k[off];
  float ss = v.x * v.x + v.y * v.y + v.z * v.z + v.w * v.w;
  #pragma unroll
  for (int m = 1; m < 64; m <<= 1) ss += __shfl_xor(ss, m, 64);
  const float nrm = sqrtf(ss);
  const float sc = 1.0f / fmaxf(nrm, 1e-12f);
  v.x *= sc; v.y *= sc; v.z *= sc; v.w *= sc;
  *(float4*)&k[off] = v;
}

__global__ __launch_bounds__(256) void etaalpha_k(
    const float* __restrict__ se, const float* __restrict__ sa,
    const float* __restrict__ We2, const float* __restrict__ be2,
    const float* __restrict__ Wa2, const float* __restrict__ ba2,
    float* __restrict__ eta, float* __restrict__ alpha)
{
  const int lane = threadIdx.x & 63;
  const size_t row = ((size_t)blockIdx.x << 2) + (threadIdx.x >> 6);
  float pe = se[row * DQ_ + lane] * We2[lane];
  float pa = sa[row * DQ_ + lane] * Wa2[lane];
  #pragma unroll
  for (int m = 1; m < 64; m <<= 1) {
    pe += __shfl_xor(pe, m, 64);
    pa += __shfl_xor(pa, m, 64);
  }
  if (lane == 0) {
    eta[row]   = sigmoid_f(pe + be2[0]) * 0.1f + 0.01f;
    alpha[row] = sigmoid_f(pa + ba2[0]) * 0.5f + 0.5f;
  }
}

__global__ __launch_bounds__(256) void ln_k(
    const float* __restrict__ t, const float* __restrict__ x,
    const float* __restrict__ gamma, const float* __restrict__ beta,
    float* __restrict__ y)
{
  const int lane = threadIdx.x & 63;
  const size_t row = ((size_t)blockIdx.x << 2) + (threadIdx.x >> 6);
  const size_t off = row * F_ + ((size_t)lane << 2);
  const float4 tv = *(const float4*)&t[off];
  const float4 xv = *(const float4*)&x[off];
  float4 v = make_float4(tv.x + xv.x, tv.y + xv.y, tv.z + xv.z, tv.w + xv.w);
  float sm = v.x + v.y + v.z + v.w;
  float sq = v.x * v.x + v.y * v.y + v.z * v.z + v.w * v.w;
  #pragma unroll
  for (int m = 1; m < 64; m <<= 1) {
    sm += __shfl_xor(sm, m, 64);
    sq += __shfl_xor(sq, m, 64);
  }
  const float mu  = sm * (1.0f / 256.0f);
  const float var = sq * (1.0f / 256.0f) - mu * mu;
  const float rstd = rsqrtf(var + 1e-5f);
  const float4 g = *(const float4*)&gamma[(size_t)lane << 2];
  const float4 b = *(const float4*)&beta[(size_t)lane << 2];
  float4 o;
  o.x = (v.x - mu) * rstd * g.x + b.x;
  o.y = (v.y - mu) * rstd * g.y + b.y;
  o.z = (v.z - mu) * rstd * g.z + b.z;
  o.w = (v.w - mu) * rstd * g.w + b.w;
  *(float4*)&y[off] = o;
}

// Gated delta-rule scan. Grid (16 row-blocks, 16 heads), block 256.
// Thread (row=tid>>4, sub=tid&15) owns M[rb*16+row][sub*16 .. +16) in regs.
// LDS q/k layout permuted: element c=sub*16+u*4+w of row t stored at
// t*256 + u*64 + sub*4 + w  -> per-t reads are 16 contiguous float4 (bank-even);
// staging stores are bank-even too.
// Decay rescaling: M = p * N;  N[j] += (c/p)*k[j].
__global__ __launch_bounds__(256, 1) void scan_k(
    const float* __restrict__ q, const float* __restrict__ kn,
    const float* __restrict__ vh, const float* __restrict__ eta,
    const float* __restrict__ alpha, float* __restrict__ out,
    float* __restrict__ Mout)
{
  __shared__ float qs[CH_ * F_];
  __shared__ float ks[CH_ * F_];
  __shared__ float vs[CH_ * 16];
  __shared__ float es[CH_];
  __shared__ float as_[CH_];
  __shared__ float os[CH_ * 16];

  const int tid = threadIdx.x;
  const int row = tid >> 4;
  const int sub = tid & 15;
  const int rb = blockIdx.x;
  const int h  = blockIdx.y;
  const int ig = rb * 16 + row;

  const float* qh  = q   + (size_t)h * S_ * F_;
  const float* kh  = kn  + (size_t)h * S_ * F_;
  const float* vhh = vh  + (size_t)h * S_ * F_ + rb * 16;
  const float* eh  = eta   + (size_t)h * S_;
  const float* ah  = alpha + (size_t)h * S_;

  float M[16];
  #pragma unroll
  for (int j = 0; j < 16; ++j) M[j] = 0.0f;

  float4 pq[4], pk[4];
  float pv = 0.0f, pea = 0.0f;

  auto loadchunk = [&](int t0) {
    #pragma unroll
    for (int r = 0; r < 4; ++r) {
      const int idx = (r << 8) + tid;   // 0..1023
      const int t = idx >> 6;           // 0..15
      const int b = idx & 63;
      pq[r] = *(const float4*)&qh[(size_t)(t0 + t) * F_ + (b << 2)];
      pk[r] = *(const float4*)&kh[(size_t)(t0 + t) * F_ + (b << 2)];
    }
    pv = vhh[(size_t)(t0 + (tid >> 4)) * F_ + (tid & 15)];
    if (tid < CH_)           pea = eh[t0 + tid];
    else if (tid < 2 * CH_)  pea = ah[t0 + tid - CH_];
  };

  loadchunk(0);

  for (int t0 = 0; t0 < S_; t0 += CH_) {
    #pragma unroll
    for (int r = 0; r < 4; ++r) {
      const int idx = (r << 8) + tid;
      const int t = idx >> 6;
      const int b = idx & 63;
      const int pos = (t << 8) + ((b & 3) << 6) + ((b >> 2) << 2);
      *(float4*)&qs[pos] = pq[r];
      *(float4*)&ks[pos] = pk[r];
    }
    vs[tid] = pv;
    if (tid < CH_)           es[tid] = pea;
    else if (tid < 2 * CH_)  as_[tid - CH_] = pea;
    __syncthreads();

    if (t0 + CH_ < S_) loadchunk(t0 + CH_);   // async-stage: drains under compute

    float p = 1.0f;
    #pragma unroll
    for (int t = 0; t < CH_; ++t) {
      float4 q4[4], k4[4];
      #pragma unroll
      for (int u = 0; u < 4; ++u) {
        const int pos = (t << 8) + (u << 6) + (sub << 2);
        q4[u] = *(const float4*)&qs[pos];
        k4[u] = *(const float4*)&ks[pos];
      }
      float dqa[4], dka[4];
      #pragma unroll
      for (int u = 0; u < 4; ++u) {
        const float* mp = &M[u << 2];
        dqa[u] = mp[0] * q4[u].x + mp[1] * q4[u].y + mp[2] * q4[u].z + mp[3] * q4[u].w;
        dka[u] = mp[0] * k4[u].x + mp[1] * k4[u].y + mp[2] * k4[u].z + mp[3] * k4[u].w;
      }
      float dq = (dqa[0] + dqa[1]) + (dqa[2] + dqa[3]);
      float dk = (dka[0] + dka[1]) + (dka[2] + dka[3]);
      dq = red16(dq);
      dk = red16(dk);
      const float pprev = p;
      dq *= pprev;
      dk *= pprev;
      if (sub == 0) os[(t << 4) + row] = dq;
      p *= as_[t];
      const float c_ = es[t] * (vs[(t << 4) + row] - dk);
      const float g  = c_ * __builtin_amdgcn_rcpf(p);
      #pragma unroll
      for (int u = 0; u < 4; ++u) {
        M[(u << 2) + 0] += g * k4[u].x;
        M[(u << 2) + 1] += g * k4[u].y;
        M[(u << 2) + 2] += g * k4[u].z;
        M[(u << 2) + 3] += g * k4[u].w;
      }
    }
    #pragma unroll
    for (int j = 0; j < 16; ++j) M[j] *= p;
    __syncthreads();

    {
      const int t = tid >> 4, r = tid & 15;
      out[((size_t)h * S_ + t0 + t) * F_ + (rb << 4) + r] = os[tid];
    }
  }

  float* mo = Mout + (size_t)h * F_ * F_ + (size_t)ig * F_ + (sub << 4);
  #pragma unroll
  for (int u = 0; u < 4; ++u) {
    *(float4*)&mo[u << 2] =
        make_float4(M[(u << 2) + 0], M[(u << 2) + 1], M[(u << 2) + 2], M[(u << 2) + 3]);
  }
}

extern "C" void kernel_launch(void* const* d_in, const int* in_sizes, int n_in,
                              void* d_out, int out_size, void* d_ws, size_t ws_size,
                              hipStream_t stream)
{
  const float* x    = (const float*)d_in[0];
  const float* Wq   = (const float*)d_in[1];
  const float* Wk   = (const float*)d_in[2];
  const float* Wv   = (const float*)d_in[3];
  const float* Wg1  = (const float*)d_in[4];
  const float* bg1  = (const float*)d_in[5];
  const float* Wg2  = (const float*)d_in[6];
  const float* bg2  = (const float*)d_in[7];
  const float* We1  = (const float*)d_in[8];
  const float* be1  = (const float*)d_in[9];
  const float* We2  = (const float*)d_in[10];
  const float* be2  = (const float*)d_in[11];
  const float* Wa1  = (const float*)d_in[12];
  const float* ba1  = (const float*)d_in[13];
  const float* Wa2  = (const float*)d_in[14];
  const float* ba2  = (const float*)d_in[15];
  const float* Wo   = (const float*)d_in[16];
  const float* bo   = (const float*)d_in[17];
  const float* gamma= (const float*)d_in[18];
  const float* beta = (const float*)d_in[19];

  const int Mrows = NH_ * S_;               // 8192
  const size_t NTF = (size_t)Mrows * F_;    // 2097152

  float* ws   = (float*)d_ws;
  float* q    = ws;
  float* kbuf = ws + NTF;
  float* vbuf = ws + 2 * NTF;
  float* tbuf = ws + 3 * NTF;
  float* eta  = ws + 4 * NTF;
  float* alpha= eta + Mrows;

  dim3 gblk(128);
  dim3 g256(F_ / 64, Mrows / 64);   // (4,128) = 512 blocks
  dim3 g64(DQ_ / 64, Mrows / 64);   // (1,128)
  dim3 blk(256);

  gemm_f32_k<<<g256, gblk, 0, stream>>>(x, Wq, nullptr, q,    Mrows, F_, F_, 0);
  gemm_f32_k<<<g256, gblk, 0, stream>>>(x, Wk, nullptr, kbuf, Mrows, F_, F_, 0);
  gemm_f32_k<<<g256, gblk, 0, stream>>>(x, Wv, nullptr, vbuf, Mrows, F_, F_, 0);
  knorm_k<<<Mrows / 4, blk, 0, stream>>>(kbuf);

  gemm_f32_k<<<g256, gblk, 0, stream>>>(vbuf, Wg1, bg1, tbuf, Mrows, F_, F_, 1);
  gemm_f32_k<<<g256, gblk, 0, stream>>>(tbuf, Wg2, bg2, vbuf, Mrows, F_, F_, 0);

  float* se = tbuf;
  float* sa = tbuf + (size_t)Mrows * DQ_;
  gemm_f32_k<<<g64, gblk, 0, stream>>>(x, We1, be1, se, Mrows, DQ_, F_, 1);
  gemm_f32_k<<<g64, gblk, 0, stream>>>(x, Wa1, ba1, sa, Mrows, DQ_, F_, 1);
  etaalpha_k<<<Mrows / 4, blk, 0, stream>>>(se, sa, We2, be2, Wa2, ba2, eta, alpha);

  float* yout = (float*)d_out;
  float* Mfin = yout + NTF;

  scan_k<<<dim3(16, 16), blk, 0, stream>>>(q, kbuf, vbuf, eta, alpha, tbuf, Mfin);

  gemm_f32_k<<<g256, gblk, 0, stream>>>(tbuf, Wo, bo, q, Mrows, F_, F_, 0);
  ln_k<<<Mrows / 4, blk, 0, stream>>>(q, x, gamma, beta, yout);
}

// Round 3
// 321.814 us; speedup vs baseline: 1.2206x; 1.2206x over previous
//
#include <hip/hip_runtime.h>

#define F_ 256
#define S_ 512
#define NH_ 16
#define DQ_ 64
#define CH_ 16

__device__ __forceinline__ float sigmoid_f(float x) { return 1.0f / (1.0f + __expf(-x)); }

template<int CTRL>
__device__ __forceinline__ float dpp_add(float x) {
  int y = __builtin_amdgcn_update_dpp(0, __float_as_int(x), CTRL, 0xf, 0xf, true);
  return x + __int_as_float(y);
}

// butterfly sum over each aligned 16-lane group; result broadcast to all 16 lanes
__device__ __forceinline__ float red16(float x) {
  x = dpp_add<0xB1>(x);   // quad_perm [1,0,3,2]
  x = dpp_add<0x4E>(x);   // quad_perm [2,3,0,1]
  x = dpp_add<0x141>(x);  // row_half_mirror
  x = dpp_add<0x140>(x);  // row_mirror
  return x;
}

// C = act(A @ W + bias); A: MxK row-major, W: KxN row-major.
// BM=BN=64, BK=32, 256 threads, 4x4 acc per thread (round-1 structure).
// A-tile stored transposed As[k][m ^ key(k)], key(k) = ((k>>2)&7)<<2:
// XOR swizzle makes the scalar transpose-stores conflict-free while
// keeping 16B-aligned float4 reads.
__global__ __launch_bounds__(256) void gemm_f32_k(
    const float* __restrict__ A, const float* __restrict__ W,
    const float* __restrict__ bias, float* __restrict__ C,
    int M, int N, int K, int act)
{
  __shared__ float As[32][64];
  __shared__ float Bs[32][64];
  const int tid = threadIdx.x;
  const int tx = tid & 15;
  const int ty = tid >> 4;
  const int row0 = blockIdx.y * 64;
  const int col0 = blockIdx.x * 64;
  float acc[4][4];
  #pragma unroll
  for (int i = 0; i < 4; ++i)
    #pragma unroll
    for (int j = 0; j < 4; ++j) acc[i][j] = 0.0f;

  for (int k0 = 0; k0 < K; k0 += 32) {
    #pragma unroll
    for (int p = 0; p < 2; ++p) {
      {
        const int r  = p * 32 + (tid >> 3);
        const int kk = (tid & 7) << 2;
        const int cs = r ^ ((tid & 7) << 2);   // swizzled m-coordinate
        const float4 av = *(const float4*)&A[(size_t)(row0 + r) * K + k0 + kk];
        As[kk + 0][cs] = av.x;
        As[kk + 1][cs] = av.y;
        As[kk + 2][cs] = av.z;
        As[kk + 3][cs] = av.w;
      }
      {
        const int rb = p * 16 + ty;
        const int cc = tx << 2;
        *(float4*)&Bs[rb][cc] = *(const float4*)&W[(size_t)(k0 + rb) * N + col0 + cc];
      }
    }
    __syncthreads();
    #pragma unroll
    for (int kk = 0; kk < 32; ++kk) {
      const int ca = (ty << 2) ^ (((kk >> 2) & 7) << 2);
      const float4 a4 = *(const float4*)&As[kk][ca];
      const float4 b4 = *(const float4*)&Bs[kk][tx << 2];
      const float av[4] = {a4.x, a4.y, a4.z, a4.w};
      const float bv[4] = {b4.x, b4.y, b4.z, b4.w};
      #pragma unroll
      for (int i = 0; i < 4; ++i)
        #pragma unroll
        for (int j = 0; j < 4; ++j)
          acc[i][j] += av[i] * bv[j];
    }
    __syncthreads();
  }

  #pragma unroll
  for (int i = 0; i < 4; ++i) {
    const int row = row0 + (ty << 2) + i;
    const int col = col0 + (tx << 2);
    float4 r = make_float4(acc[i][0], acc[i][1], acc[i][2], acc[i][3]);
    if (bias) {
      const float4 b = *(const float4*)&bias[col];
      r.x += b.x; r.y += b.y; r.z += b.z; r.w += b.w;
    }
    if (act == 1) {
      r.x *= sigmoid_f(r.x); r.y *= sigmoid_f(r.y);
      r.z *= sigmoid_f(r.z); r.w *= sigmoid_f(r.w);
    }
    *(float4*)&C[(size_t)row * N + col] = r;
  }
}

// in-place row L2-normalize, one wave per 256-float row
__global__ __launch_bounds__(256) void knorm_k(float* __restrict__ k)
{
  const int lane = threadIdx.x & 63;
  const size_t row = ((size_t)blockIdx.x << 2) + (threadIdx.x >> 6);
  const size_t off = row * F_ + ((size_t)lane << 2);
  float4 v = *(float4*)&k[off];
  float ss = v.x * v.x + v.y * v.y + v.z * v.z + v.w * v.w;
  #pragma unroll
  for (int m = 1; m < 64; m <<= 1) ss += __shfl_xor(ss, m, 64);
  const float nrm = sqrtf(ss);
  const float sc = 1.0f / fmaxf(nrm, 1e-12f);
  v.x *= sc; v.y *= sc; v.z *= sc; v.w *= sc;
  *(float4*)&k[off] = v;
}

__global__ __launch_bounds__(256) void etaalpha_k(
    const float* __restrict__ se, const float* __restrict__ sa,
    const float* __restrict__ We2, const float* __restrict__ be2,
    const float* __restrict__ Wa2, const float* __restrict__ ba2,
    float* __restrict__ eta, float* __restrict__ alpha)
{
  const int lane = threadIdx.x & 63;
  const size_t row = ((size_t)blockIdx.x << 2) + (threadIdx.x >> 6);
  float pe = se[row * DQ_ + lane] * We2[lane];
  float pa = sa[row * DQ_ + lane] * Wa2[lane];
  #pragma unroll
  for (int m = 1; m < 64; m <<= 1) {
    pe += __shfl_xor(pe, m, 64);
    pa += __shfl_xor(pa, m, 64);
  }
  if (lane == 0) {
    eta[row]   = sigmoid_f(pe + be2[0]) * 0.1f + 0.01f;
    alpha[row] = sigmoid_f(pa + ba2[0]) * 0.5f + 0.5f;
  }
}

__global__ __launch_bounds__(256) void ln_k(
    const float* __restrict__ t, const float* __restrict__ x,
    const float* __restrict__ gamma, const float* __restrict__ beta,
    float* __restrict__ y)
{
  const int lane = threadIdx.x & 63;
  const size_t row = ((size_t)blockIdx.x << 2) + (threadIdx.x >> 6);
  const size_t off = row * F_ + ((size_t)lane << 2);
  const float4 tv = *(const float4*)&t[off];
  const float4 xv = *(const float4*)&x[off];
  float4 v = make_float4(tv.x + xv.x, tv.y + xv.y, tv.z + xv.z, tv.w + xv.w);
  float sm = v.x + v.y + v.z + v.w;
  float sq = v.x * v.x + v.y * v.y + v.z * v.z + v.w * v.w;
  #pragma unroll
  for (int m = 1; m < 64; m <<= 1) {
    sm += __shfl_xor(sm, m, 64);
    sq += __shfl_xor(sq, m, 64);
  }
  const float mu  = sm * (1.0f / 256.0f);
  const float var = sq * (1.0f / 256.0f) - mu * mu;
  const float rstd = rsqrtf(var + 1e-5f);
  const float4 g = *(const float4*)&gamma[(size_t)lane << 2];
  const float4 b = *(const float4*)&beta[(size_t)lane << 2];
  float4 o;
  o.x = (v.x - mu) * rstd * g.x + b.x;
  o.y = (v.y - mu) * rstd * g.y + b.y;
  o.z = (v.z - mu) * rstd * g.z + b.z;
  o.w = (v.w - mu) * rstd * g.w + b.w;
  *(float4*)&y[off] = o;
}

// Gated delta-rule scan. Grid (16 row-blocks, 16 heads), block 256.
// Thread (row=tid>>4, sub=tid&15) owns M[rb*16+row][sub*16 .. +16) in regs.
// LDS q/k permuted: element c=sub*16+u*4+w of row t at t*256+u*64+sub*4+w.
// Inner loop: 2-deep ping-pong register pipeline (LD t+1 issued before STEP t)
// so ds_read latency hides under the ~130-cycle dependent chain of each step.
// Decay rescaling M = p*N; step chain reduced to dk -> fma -> fma via
// A_ = e*v*rcp(p), B_ = e*pprev*rcp(p) computed off-chain.
__global__ __launch_bounds__(256, 1) void scan_k(
    const float* __restrict__ q, const float* __restrict__ kn,
    const float* __restrict__ vh, const float* __restrict__ eta,
    const float* __restrict__ alpha, float* __restrict__ out,
    float* __restrict__ Mout)
{
  __shared__ float qs[CH_ * F_];
  __shared__ float ks[CH_ * F_];
  __shared__ float vs[CH_ * 16];
  __shared__ float es[CH_];
  __shared__ float as_[CH_];
  __shared__ float os[CH_ * 16];

  const int tid = threadIdx.x;
  const int row = tid >> 4;
  const int sub = tid & 15;
  const int rb = blockIdx.x;
  const int h  = blockIdx.y;
  const int ig = rb * 16 + row;

  const float* qh  = q   + (size_t)h * S_ * F_;
  const float* kh  = kn  + (size_t)h * S_ * F_;
  const float* vhh = vh  + (size_t)h * S_ * F_ + rb * 16;
  const float* eh  = eta   + (size_t)h * S_;
  const float* ah  = alpha + (size_t)h * S_;

  float M[16];
  #pragma unroll
  for (int j = 0; j < 16; ++j) M[j] = 0.0f;

  float4 pq[4], pk[4];
  float pv = 0.0f, pea = 0.0f;

  auto loadchunk = [&](int t0) {
    #pragma unroll
    for (int r = 0; r < 4; ++r) {
      const int idx = (r << 8) + tid;   // 0..1023
      const int t = idx >> 6;           // 0..15
      const int b = idx & 63;
      pq[r] = *(const float4*)&qh[(size_t)(t0 + t) * F_ + (b << 2)];
      pk[r] = *(const float4*)&kh[(size_t)(t0 + t) * F_ + (b << 2)];
    }
    pv = vhh[(size_t)(t0 + (tid >> 4)) * F_ + (tid & 15)];
    if (tid < CH_)           pea = eh[t0 + tid];
    else if (tid < 2 * CH_)  pea = ah[t0 + tid - CH_];
  };

  loadchunk(0);

  float p = 1.0f;   // running decay product within chunk

  auto LD = [&](int t, float4 (&Q)[4], float4 (&K)[4],
                float& e_, float& a_, float& v_) {
    #pragma unroll
    for (int u = 0; u < 4; ++u) {
      const int pos = (t << 8) + (u << 6) + (sub << 2);
      Q[u] = *(const float4*)&qs[pos];
      K[u] = *(const float4*)&ks[pos];
    }
    e_ = es[t]; a_ = as_[t]; v_ = vs[(t << 4) + row];
  };

  auto STEP = [&](int t, const float4 (&Q)[4], const float4 (&K)[4],
                  float e_, float a_, float v_) {
    float dqa[4], dka[4];
    #pragma unroll
    for (int u = 0; u < 4; ++u) {
      const float* mp = &M[u << 2];
      dqa[u] = mp[0] * Q[u].x + mp[1] * Q[u].y + mp[2] * Q[u].z + mp[3] * Q[u].w;
      dka[u] = mp[0] * K[u].x + mp[1] * K[u].y + mp[2] * K[u].z + mp[3] * K[u].w;
    }
    float dq = (dqa[0] + dqa[1]) + (dqa[2] + dqa[3]);
    float dk = (dka[0] + dka[1]) + (dka[2] + dka[3]);
    dq = red16(dq);
    dk = red16(dk);
    const float pprev = p;
    p = pprev * a_;
    const float r_  = __builtin_amdgcn_rcpf(p);
    const float A_  = (e_ * v_) * r_;        // off critical chain
    const float B_  = (e_ * pprev) * r_;     // off critical chain
    if (sub == 0) os[(t << 4) + row] = dq * pprev;
    const float g = A_ - B_ * dk;            // single fma on the chain
    #pragma unroll
    for (int u = 0; u < 4; ++u) {
      M[(u << 2) + 0] += g * K[u].x;
      M[(u << 2) + 1] += g * K[u].y;
      M[(u << 2) + 2] += g * K[u].z;
      M[(u << 2) + 3] += g * K[u].w;
    }
  };

  for (int t0 = 0; t0 < S_; t0 += CH_) {
    // commit prefetched chunk into LDS (permuted layout)
    #pragma unroll
    for (int r = 0; r < 4; ++r) {
      const int idx = (r << 8) + tid;
      const int t = idx >> 6;
      const int b = idx & 63;
      const int pos = (t << 8) + ((b & 3) << 6) + ((b >> 2) << 2);
      *(float4*)&qs[pos] = pq[r];
      *(float4*)&ks[pos] = pk[r];
    }
    vs[tid] = pv;
    if (tid < CH_)           es[tid] = pea;
    else if (tid < 2 * CH_)  as_[tid - CH_] = pea;
    __syncthreads();

    if (t0 + CH_ < S_) loadchunk(t0 + CH_);   // global prefetch drains under compute

    p = 1.0f;
    float4 qA[4], kA[4], qB[4], kB[4];
    float eA, aA, vA, eB, aB, vB;
    LD(0, qA, kA, eA, aA, vA);
    #pragma unroll
    for (int t = 0; t < CH_; t += 2) {
      LD(t + 1, qB, kB, eB, aB, vB);     // issue reads for t+1 before computing t
      STEP(t, qA, kA, eA, aA, vA);
      if (t + 2 < CH_) LD(t + 2, qA, kA, eA, aA, vA);
      STEP(t + 1, qB, kB, eB, aB, vB);
    }
    #pragma unroll
    for (int j = 0; j < 16; ++j) M[j] *= p;   // fold decay product back
    __syncthreads();

    {
      const int t = tid >> 4, r = tid & 15;
      out[((size_t)h * S_ + t0 + t) * F_ + (rb << 4) + r] = os[tid];
    }
  }

  float* mo = Mout + (size_t)h * F_ * F_ + (size_t)ig * F_ + (sub << 4);
  #pragma unroll
  for (int u = 0; u < 4; ++u) {
    *(float4*)&mo[u << 2] =
        make_float4(M[(u << 2) + 0], M[(u << 2) + 1], M[(u << 2) + 2], M[(u << 2) + 3]);
  }
}

extern "C" void kernel_launch(void* const* d_in, const int* in_sizes, int n_in,
                              void* d_out, int out_size, void* d_ws, size_t ws_size,
                              hipStream_t stream)
{
  const float* x    = (const float*)d_in[0];
  const float* Wq   = (const float*)d_in[1];
  const float* Wk   = (const float*)d_in[2];
  const float* Wv   = (const float*)d_in[3];
  const float* Wg1  = (const float*)d_in[4];
  const float* bg1  = (const float*)d_in[5];
  const float* Wg2  = (const float*)d_in[6];
  const float* bg2  = (const float*)d_in[7];
  const float* We1  = (const float*)d_in[8];
  const float* be1  = (const float*)d_in[9];
  const float* We2  = (const float*)d_in[10];
  const float* be2  = (const float*)d_in[11];
  const float* Wa1  = (const float*)d_in[12];
  const float* ba1  = (const float*)d_in[13];
  const float* Wa2  = (const float*)d_in[14];
  const float* ba2  = (const float*)d_in[15];
  const float* Wo   = (const float*)d_in[16];
  const float* bo   = (const float*)d_in[17];
  const float* gamma= (const float*)d_in[18];
  const float* beta = (const float*)d_in[19];

  const int Mrows = NH_ * S_;               // 8192
  const size_t NTF = (size_t)Mrows * F_;    // 2097152

  float* ws   = (float*)d_ws;
  float* q    = ws;
  float* kbuf = ws + NTF;
  float* vbuf = ws + 2 * NTF;
  float* tbuf = ws + 3 * NTF;
  float* eta  = ws + 4 * NTF;
  float* alpha= eta + Mrows;

  dim3 blk(256);
  dim3 g256(F_ / 64, Mrows / 64);   // (4,128) = 512 blocks
  dim3 g64(DQ_ / 64, Mrows / 64);   // (1,128)

  gemm_f32_k<<<g256, blk, 0, stream>>>(x, Wq, nullptr, q,    Mrows, F_, F_, 0);
  gemm_f32_k<<<g256, blk, 0, stream>>>(x, Wk, nullptr, kbuf, Mrows, F_, F_, 0);
  gemm_f32_k<<<g256, blk, 0, stream>>>(x, Wv, nullptr, vbuf, Mrows, F_, F_, 0);
  knorm_k<<<Mrows / 4, blk, 0, stream>>>(kbuf);

  gemm_f32_k<<<g256, blk, 0, stream>>>(vbuf, Wg1, bg1, tbuf, Mrows, F_, F_, 1);
  gemm_f32_k<<<g256, blk, 0, stream>>>(tbuf, Wg2, bg2, vbuf, Mrows, F_, F_, 0);

  float* se = tbuf;
  float* sa = tbuf + (size_t)Mrows * DQ_;
  gemm_f32_k<<<g64, blk, 0, stream>>>(x, We1, be1, se, Mrows, DQ_, F_, 1);
  gemm_f32_k<<<g64, blk, 0, stream>>>(x, Wa1, ba1, sa, Mrows, DQ_, F_, 1);
  etaalpha_k<<<Mrows / 4, blk, 0, stream>>>(se, sa, We2, be2, Wa2, ba2, eta, alpha);

  float* yout = (float*)d_out;
  float* Mfin = yout + NTF;

  scan_k<<<dim3(16, 16), blk, 0, stream>>>(q, kbuf, vbuf, eta, alpha, tbuf, Mfin);

  gemm_f32_k<<<g256, blk, 0, stream>>>(tbuf, Wo, bo, q, Mrows, F_, F_, 0);
  ln_k<<<Mrows / 4, blk, 0, stream>>>(q, x, gamma, beta, yout);
}

// Round 4
// 212.733 us; speedup vs baseline: 1.8464x; 1.5128x over previous
//
#include <hip/hip_runtime.h>

#define F_ 256
#define S_ 512
#define NH_ 16
#define DQ_ 64
#define CCH 32
#define NCH (S_/CCH)
#define KSTR 264   // padded bf16 row stride for [32][256] LDS tiles
#define TSTR 40    // padded bf16 row stride for [32][32]/[16][32] LDS tiles

typedef __attribute__((ext_vector_type(8))) short short8_t;
typedef __attribute__((ext_vector_type(4))) float f32x4;

__device__ __forceinline__ float sigmoid_f(float x) { return 1.0f / (1.0f + __expf(-x)); }

__device__ __forceinline__ ushort f2bf(float x) {   // RNE float->bf16
  uint u = __float_as_uint(x);
  u += 0x7FFFu + ((u >> 16) & 1u);
  return (ushort)(u >> 16);
}

template<int CTRL>
__device__ __forceinline__ float dpp_add(float x) {
  int y = __builtin_amdgcn_update_dpp(0, __float_as_int(x), CTRL, 0xf, 0xf, true);
  return x + __int_as_float(y);
}
// butterfly sum over aligned 8-lane groups, result in all 8 lanes
__device__ __forceinline__ float red8(float x) {
  x = dpp_add<0xB1>(x);   // xor 1
  x = dpp_add<0x4E>(x);   // xor 2
  x = dpp_add<0x141>(x);  // row_half_mirror (within 8)
  return x;
}

// C = act(A @ W + bias); optional f32 out C and/or bf16 out Cb.
__global__ __launch_bounds__(256) void gemm_f32_k(
    const float* __restrict__ A, const float* __restrict__ W,
    const float* __restrict__ bias, float* __restrict__ C,
    ushort* __restrict__ Cb,
    int M, int N, int K, int act)
{
  __shared__ float As[32][64];
  __shared__ float Bs[32][64];
  const int tid = threadIdx.x;
  const int tx = tid & 15;
  const int ty = tid >> 4;
  const int row0 = blockIdx.y * 64;
  const int col0 = blockIdx.x * 64;
  float acc[4][4];
  #pragma unroll
  for (int i = 0; i < 4; ++i)
    #pragma unroll
    for (int j = 0; j < 4; ++j) acc[i][j] = 0.0f;

  for (int k0 = 0; k0 < K; k0 += 32) {
    #pragma unroll
    for (int p = 0; p < 2; ++p) {
      {
        const int r  = p * 32 + (tid >> 3);
        const int kk = (tid & 7) << 2;
        const int cs = r ^ ((tid & 7) << 2);
        const float4 av = *(const float4*)&A[(size_t)(row0 + r) * K + k0 + kk];
        As[kk + 0][cs] = av.x;
        As[kk + 1][cs] = av.y;
        As[kk + 2][cs] = av.z;
        As[kk + 3][cs] = av.w;
      }
      {
        const int rb = p * 16 + ty;
        const int cc = tx << 2;
        *(float4*)&Bs[rb][cc] = *(const float4*)&W[(size_t)(k0 + rb) * N + col0 + cc];
      }
    }
    __syncthreads();
    #pragma unroll
    for (int kk = 0; kk < 32; ++kk) {
      const int ca = (ty << 2) ^ (((kk >> 2) & 7) << 2);
      const float4 a4 = *(const float4*)&As[kk][ca];
      const float4 b4 = *(const float4*)&Bs[kk][tx << 2];
      const float av[4] = {a4.x, a4.y, a4.z, a4.w};
      const float bv[4] = {b4.x, b4.y, b4.z, b4.w};
      #pragma unroll
      for (int i = 0; i < 4; ++i)
        #pragma unroll
        for (int j = 0; j < 4; ++j)
          acc[i][j] += av[i] * bv[j];
    }
    __syncthreads();
  }

  #pragma unroll
  for (int i = 0; i < 4; ++i) {
    const int row = row0 + (ty << 2) + i;
    const int col = col0 + (tx << 2);
    float4 r = make_float4(acc[i][0], acc[i][1], acc[i][2], acc[i][3]);
    if (bias) {
      const float4 b = *(const float4*)&bias[col];
      r.x += b.x; r.y += b.y; r.z += b.z; r.w += b.w;
    }
    if (act == 1) {
      r.x *= sigmoid_f(r.x); r.y *= sigmoid_f(r.y);
      r.z *= sigmoid_f(r.z); r.w *= sigmoid_f(r.w);
    }
    if (C)  *(float4*)&C[(size_t)row * N + col] = r;
    if (Cb) {
      ushort4 hv;
      hv.x = f2bf(r.x); hv.y = f2bf(r.y); hv.z = f2bf(r.z); hv.w = f2bf(r.w);
      *(ushort4*)&Cb[(size_t)row * N + col] = hv;
    }
  }
}

// k-row L2 normalize, output bf16 only
__global__ __launch_bounds__(256) void knorm_k(const float* __restrict__ k,
                                               ushort* __restrict__ kb)
{
  const int lane = threadIdx.x & 63;
  const size_t row = ((size_t)blockIdx.x << 2) + (threadIdx.x >> 6);
  const size_t off = row * F_ + ((size_t)lane << 2);
  float4 v = *(const float4*)&k[off];
  float ss = v.x * v.x + v.y * v.y + v.z * v.z + v.w * v.w;
  #pragma unroll
  for (int m = 1; m < 64; m <<= 1) ss += __shfl_xor(ss, m, 64);
  const float sc = 1.0f / fmaxf(sqrtf(ss), 1e-12f);
  ushort4 o;
  o.x = f2bf(v.x * sc); o.y = f2bf(v.y * sc);
  o.z = f2bf(v.z * sc); o.w = f2bf(v.w * sc);
  *(ushort4*)&kb[off] = o;
}

__global__ __launch_bounds__(256) void etaalpha_k(
    const float* __restrict__ se, const float* __restrict__ sa,
    const float* __restrict__ We2, const float* __restrict__ be2,
    const float* __restrict__ Wa2, const float* __restrict__ ba2,
    float* __restrict__ eta, float* __restrict__ alpha)
{
  const int lane = threadIdx.x & 63;
  const size_t row = ((size_t)blockIdx.x << 2) + (threadIdx.x >> 6);
  float pe = se[row * DQ_ + lane] * We2[lane];
  float pa = sa[row * DQ_ + lane] * Wa2[lane];
  #pragma unroll
  for (int m = 1; m < 64; m <<= 1) {
    pe += __shfl_xor(pe, m, 64);
    pa += __shfl_xor(pa, m, 64);
  }
  if (lane == 0) {
    eta[row]   = sigmoid_f(pe + be2[0]) * 0.1f + 0.01f;
    alpha[row] = sigmoid_f(pa + ba2[0]) * 0.5f + 0.5f;
  }
}

__global__ __launch_bounds__(256) void ln_k(
    const float* __restrict__ t, const float* __restrict__ x,
    const float* __restrict__ gamma, const float* __restrict__ beta,
    float* __restrict__ y)
{
  const int lane = threadIdx.x & 63;
  const size_t row = ((size_t)blockIdx.x << 2) + (threadIdx.x >> 6);
  const size_t off = row * F_ + ((size_t)lane << 2);
  const float4 tv = *(const float4*)&t[off];
  const float4 xv = *(const float4*)&x[off];
  float4 v = make_float4(tv.x + xv.x, tv.y + xv.y, tv.z + xv.z, tv.w + xv.w);
  float sm = v.x + v.y + v.z + v.w;
  float sq = v.x * v.x + v.y * v.y + v.z * v.z + v.w * v.w;
  #pragma unroll
  for (int m = 1; m < 64; m <<= 1) {
    sm += __shfl_xor(sm, m, 64);
    sq += __shfl_xor(sq, m, 64);
  }
  const float mu  = sm * (1.0f / 256.0f);
  const float var = sq * (1.0f / 256.0f) - mu * mu;
  const float rstd = rsqrtf(var + 1e-5f);
  const float4 g = *(const float4*)&gamma[(size_t)lane << 2];
  const float4 b = *(const float4*)&beta[(size_t)lane << 2];
  float4 o;
  o.x = (v.x - mu) * rstd * g.x + b.x;
  o.y = (v.y - mu) * rstd * g.y + b.y;
  o.z = (v.z - mu) * rstd * g.z + b.z;
  o.w = (v.w - mu) * rstd * g.w + b.w;
  *(float4*)&y[off] = o;
}

// ---- chunked delta-rule prep: per (chunk, head) compute G=KK^T, masked Gq=QK^T,
// decay scalars, and T = (I + strictlower(diag(b) G))^{-1}. Grid (NCH, NH).
__global__ __launch_bounds__(256) void prep_k(
    const ushort* __restrict__ kb, const ushort* __restrict__ qb,
    const float* __restrict__ eta, const float* __restrict__ alpha,
    ushort* __restrict__ Tg, ushort* __restrict__ Gqg, float* __restrict__ Sg)
{
  __shared__ ushort K_lds[CCH * KSTR];
  __shared__ ushort Q_lds[CCH * KSTR];
  __shared__ float  G_lds[CCH * CCH];
  __shared__ float  ea[2 * CCH];
  __shared__ float  scal[100];

  const int tid = threadIdx.x;
  const int ch = blockIdx.x, h = blockIdx.y;
  const int t0 = ch * CCH;
  const int l = tid & 63, wv = tid >> 6;
  const int ln = l & 15, hi = l >> 4;
  const int hi8 = hi * 8, hi4 = hi * 4;

  const ushort* kg = kb + (size_t)(h * S_ + t0) * F_;
  const ushort* qg = qb + (size_t)(h * S_ + t0) * F_;
  #pragma unroll
  for (int w = 0; w < 4; ++w) {
    int o = w * 256 + tid; int t = o >> 5, c8 = (o & 31) << 3;
    *(short8_t*)&K_lds[t * KSTR + c8] = *(const short8_t*)&kg[(size_t)t * F_ + c8];
    *(short8_t*)&Q_lds[t * KSTR + c8] = *(const short8_t*)&qg[(size_t)t * F_ + c8];
  }
  if (tid < CCH)            ea[tid] = eta[(size_t)h * S_ + t0 + tid];
  else if (tid < 2 * CCH)   ea[tid] = alpha[(size_t)h * S_ + t0 + tid - CCH];
  __syncthreads();

  {
    const int tI = wv >> 1, tJ = wv & 1;
    f32x4 accG = {0.f, 0.f, 0.f, 0.f};
    f32x4 accQ = {0.f, 0.f, 0.f, 0.f};
    #pragma unroll
    for (int ko = 0; ko < 8; ++ko) {
      const int cb = ko * 32 + hi8;
      short8_t bfr = *(const short8_t*)&K_lds[(tJ * 16 + ln) * KSTR + cb];
      short8_t aK  = *(const short8_t*)&K_lds[(tI * 16 + ln) * KSTR + cb];
      short8_t aQ  = *(const short8_t*)&Q_lds[(tI * 16 + ln) * KSTR + cb];
      accG = __builtin_amdgcn_mfma_f32_16x16x32_bf16(aK, bfr, accG, 0, 0, 0);
      accQ = __builtin_amdgcn_mfma_f32_16x16x32_bf16(aQ, bfr, accQ, 0, 0, 0);
    }
    ushort* Gqo = Gqg + (size_t)(h * NCH + ch) * (CCH * CCH);
    #pragma unroll
    for (int r = 0; r < 4; ++r) {
      const int t = tI * 16 + hi4 + r, s = tJ * 16 + ln;
      G_lds[t * CCH + s] = accG[r];
      Gqo[t * CCH + s] = (s < t) ? f2bf(accQ[r]) : (ushort)0;
    }
  }
  if (tid == 0) {
    float gp = 1.f;
    for (int t = 0; t < CCH; ++t) {
      const float a = ea[CCH + t], e = ea[t];
      const float gm = gp * a;
      scal[t]           = e / a;    // b_t
      scal[CCH + t]     = e / gm;   // c_t
      scal[2 * CCH + t] = gp;       // gamma_prev
      gp = gm;
    }
    scal[3 * CCH] = gp;             // gamma_C
  }
  __syncthreads();

  // forward substitution: column j of T, x_t = d_tj - b_t * sum_{s<t} G[t][s] x_s
  {
    const int j = tid >> 3, g = tid & 7;
    float x0 = 0.f, x1 = 0.f, x2 = 0.f, x3 = 0.f;
    ushort* To = Tg + (size_t)(h * NCH + ch) * (CCH * CCH);
    #pragma unroll
    for (int t = 0; t < CCH; ++t) {
      float p = 0.f;
      const f32x4 gr = *(const f32x4*)&G_lds[t * CCH + 4 * g];
      if (4 * g + 0 < t) p += gr[0] * x0;
      if (4 * g + 1 < t) p += gr[1] * x1;
      if (4 * g + 2 < t) p += gr[2] * x2;
      if (4 * g + 3 < t) p += gr[3] * x3;
      const float tot = red8(p);
      const float xt = ((t == j) ? 1.f : 0.f) - scal[t] * tot;
      if (g == (t >> 2)) {
        if ((t & 3) == 0) x0 = xt; else if ((t & 3) == 1) x1 = xt;
        else if ((t & 3) == 2) x2 = xt; else x3 = xt;
      }
      if (g == 0) To[t * CCH + j] = f2bf(xt);
    }
  }
  if (tid < 97) Sg[(size_t)(h * NCH + ch) * 128 + tid] = scal[tid];
}

// ---- chunked scan: grid (16 row-slices, 16 heads); block owns 16 rows of M.
__global__ __launch_bounds__(256) void scan_chunk_k(
    const ushort* __restrict__ kb, const ushort* __restrict__ qb,
    const float* __restrict__ vh,
    const ushort* __restrict__ Tg, const ushort* __restrict__ Gqg,
    const float* __restrict__ Sg,
    float* __restrict__ out, float* __restrict__ Mout)
{
  __shared__ ushort K_lds[CCH * KSTR];
  __shared__ ushort Q_lds[CCH * KSTR];
  __shared__ ushort M_lds[16 * KSTR];
  __shared__ ushort T_lds[CCH * TSTR];
  __shared__ ushort Gq_lds[CCH * TSTR];
  __shared__ ushort Wt_lds[16 * TSTR];
  __shared__ ushort R_lds[16 * TSTR];
  __shared__ float  KM_lds[CCH * 20];
  __shared__ float  QM_lds[CCH * 20];
  __shared__ float  V_lds[CCH * 16];
  __shared__ float  scal[100];

  const int tid = threadIdx.x;
  const int slice = blockIdx.x, h = blockIdx.y;
  const int r0 = slice * 16;
  const int l = tid & 63, wv = tid >> 6;
  const int ln = l & 15, hi = l >> 4;
  const int hi8 = hi * 8, hi4 = hi * 4;

  #pragma unroll 4
  for (int u = tid; u < 16 * KSTR / 8; u += 256) {
    f32x4 z = {0.f, 0.f, 0.f, 0.f};
    *(f32x4*)&M_lds[u * 8] = z;
  }
  f32x4 Mf[4];
  #pragma unroll
  for (int q = 0; q < 4; ++q)
    #pragma unroll
    for (int r = 0; r < 4; ++r) Mf[q][r] = 0.f;

  const ushort* kgh = kb + (size_t)h * S_ * F_;
  const ushort* qgh = qb + (size_t)h * S_ * F_;

  for (int ch = 0; ch < NCH; ++ch) {
    const int t0 = ch * CCH;
    // ---- stage ----
    #pragma unroll
    for (int w = 0; w < 4; ++w) {
      int o = w * 256 + tid; int t = o >> 5, c8 = (o & 31) << 3;
      *(short8_t*)&K_lds[t * KSTR + c8] = *(const short8_t*)&kgh[(size_t)(t0 + t) * F_ + c8];
      *(short8_t*)&Q_lds[t * KSTR + c8] = *(const short8_t*)&qgh[(size_t)(t0 + t) * F_ + c8];
    }
    {
      const ushort* Ti = Tg  + (size_t)(h * NCH + ch) * (CCH * CCH);
      const ushort* Gi = Gqg + (size_t)(h * NCH + ch) * (CCH * CCH);
      if (tid < 128) {
        int t = tid >> 2, c8 = (tid & 3) << 3;
        *(short8_t*)&T_lds[t * TSTR + c8] = *(const short8_t*)&Ti[t * CCH + c8];
      } else {
        int t = (tid - 128) >> 2, c8 = ((tid - 128) & 3) << 3;
        *(short8_t*)&Gq_lds[t * TSTR + c8] = *(const short8_t*)&Gi[t * CCH + c8];
      }
    }
    #pragma unroll
    for (int u = 0; u < 2; ++u) {
      int e = u * 256 + tid; int t = e >> 4, c = e & 15;
      V_lds[e] = vh[(size_t)(h * S_ + t0 + t) * F_ + r0 + c];
    }
    if (tid < 97) scal[tid] = Sg[(size_t)(h * NCH + ch) * 128 + tid];
    __syncthreads();

    // ---- KM = K M^T (waves 0,1), QM = Q M^T (waves 2,3) ----
    {
      const ushort* src = (wv < 2) ? K_lds : Q_lds;
      float* dst = (wv < 2) ? KM_lds : QM_lds;
      const int I = wv & 1;
      f32x4 acc = {0.f, 0.f, 0.f, 0.f};
      #pragma unroll
      for (int ko = 0; ko < 8; ++ko) {
        const int cb = ko * 32 + hi8;
        short8_t a = *(const short8_t*)&src[(I * 16 + ln) * KSTR + cb];
        short8_t b = *(const short8_t*)&M_lds[ln * KSTR + cb];
        acc = __builtin_amdgcn_mfma_f32_16x16x32_bf16(a, b, acc, 0, 0, 0);
      }
      #pragma unroll
      for (int r = 0; r < 4; ++r)
        dst[(I * 16 + hi4 + r) * 20 + ln] = acc[r];
    }
    __syncthreads();

    // ---- RHS_t[c] = c_t V - b_t KM  (stored transposed, bf16) ----
    #pragma unroll
    for (int u = 0; u < 2; ++u) {
      int e = u * 256 + tid; int t = e >> 4, c = e & 15;
      float rhs = scal[CCH + t] * V_lds[e] - scal[t] * KM_lds[t * 20 + c];
      R_lds[c * TSTR + t] = f2bf(rhs);
    }
    __syncthreads();

    // ---- W = T @ RHS  (waves 0,1), stored transposed ----
    if (wv < 2) {
      const int I = wv;
      short8_t a = *(const short8_t*)&T_lds[(I * 16 + ln) * TSTR + hi8];
      short8_t b = *(const short8_t*)&R_lds[ln * TSTR + hi8];
      f32x4 z = {0.f, 0.f, 0.f, 0.f};
      f32x4 d = __builtin_amdgcn_mfma_f32_16x16x32_bf16(a, b, z, 0, 0, 0);
      #pragma unroll
      for (int r = 0; r < 4; ++r)
        Wt_lds[ln * TSTR + I * 16 + hi4 + r] = f2bf(d[r]);
    }
    __syncthreads();

    // ---- intra + OUT (waves 0,1) ----
    if (wv < 2) {
      const int I = wv;
      short8_t a = *(const short8_t*)&Gq_lds[(I * 16 + ln) * TSTR + hi8];
      short8_t b = *(const short8_t*)&Wt_lds[ln * TSTR + hi8];
      f32x4 z = {0.f, 0.f, 0.f, 0.f};
      f32x4 d = __builtin_amdgcn_mfma_f32_16x16x32_bf16(a, b, z, 0, 0, 0);
      #pragma unroll
      for (int r = 0; r < 4; ++r) {
        const int t = I * 16 + hi4 + r;
        out[(size_t)(h * S_ + t0 + t) * F_ + r0 + ln] =
            scal[2 * CCH + t] * (QM_lds[t * 20 + ln] + d[r]);
      }
    }
    // ---- M update: M = gammaC * (M + W^T K)  (all waves) ----
    {
      const float gC = scal[3 * CCH];
      short8_t aw = *(const short8_t*)&Wt_lds[ln * TSTR + hi8];
      #pragma unroll
      for (int q = 0; q < 4; ++q) {
        const int jt = wv * 4 + q;
        short8_t bk;
        #pragma unroll
        for (int i = 0; i < 8; ++i)
          bk[i] = (short)K_lds[(hi8 + i) * KSTR + jt * 16 + ln];
        f32x4 d = __builtin_amdgcn_mfma_f32_16x16x32_bf16(aw, bk, Mf[q], 0, 0, 0);
        #pragma unroll
        for (int r = 0; r < 4; ++r) {
          const float nv = gC * d[r];
          Mf[q][r] = nv;
          M_lds[(hi4 + r) * KSTR + jt * 16 + ln] = f2bf(nv);
        }
      }
    }
    __syncthreads();
  }

  #pragma unroll
  for (int q = 0; q < 4; ++q) {
    const int jt = wv * 4 + q;
    #pragma unroll
    for (int r = 0; r < 4; ++r)
      Mout[((size_t)h * F_ + r0 + hi4 + r) * F_ + jt * 16 + ln] = Mf[q][r];
  }
}

extern "C" void kernel_launch(void* const* d_in, const int* in_sizes, int n_in,
                              void* d_out, int out_size, void* d_ws, size_t ws_size,
                              hipStream_t stream)
{
  const float* x    = (const float*)d_in[0];
  const float* Wq   = (const float*)d_in[1];
  const float* Wk   = (const float*)d_in[2];
  const float* Wv   = (const float*)d_in[3];
  const float* Wg1  = (const float*)d_in[4];
  const float* bg1  = (const float*)d_in[5];
  const float* Wg2  = (const float*)d_in[6];
  const float* bg2  = (const float*)d_in[7];
  const float* We1  = (const float*)d_in[8];
  const float* be1  = (const float*)d_in[9];
  const float* We2  = (const float*)d_in[10];
  const float* be2  = (const float*)d_in[11];
  const float* Wa1  = (const float*)d_in[12];
  const float* ba1  = (const float*)d_in[13];
  const float* Wa2  = (const float*)d_in[14];
  const float* ba2  = (const float*)d_in[15];
  const float* Wo   = (const float*)d_in[16];
  const float* bo   = (const float*)d_in[17];
  const float* gamma= (const float*)d_in[18];
  const float* beta = (const float*)d_in[19];

  const int Mrows = NH_ * S_;               // 8192
  const size_t NTF = (size_t)Mrows * F_;    // 2097152

  float* ws   = (float*)d_ws;
  // slot 0: qb (bf16, NTF) + kb (bf16, NTF)  -> later reused as f32 tmp
  ushort* qb  = (ushort*)ws;
  ushort* kb  = qb + NTF;
  float* tmp0 = ws;
  // slot 1: k f32 (Wk output), later prep outputs T/Gq/scal
  float* kbuf = ws + NTF;
  ushort* Tg  = (ushort*)kbuf;
  ushort* Gqg = Tg + (size_t)NH_ * NCH * CCH * CCH;
  float*  Sg  = (float*)(Gqg + (size_t)NH_ * NCH * CCH * CCH);
  // slot 2: v -> v_hat
  float* vbuf = ws + 2 * NTF;
  // slot 3: t1 -> se/sa -> scan out
  float* tbuf = ws + 3 * NTF;
  float* eta  = ws + 4 * NTF;
  float* alpha= eta + Mrows;

  dim3 blk(256);
  dim3 g256(F_ / 64, Mrows / 64);   // (4,128)
  dim3 g64(DQ_ / 64, Mrows / 64);   // (1,128)

  gemm_f32_k<<<g256, blk, 0, stream>>>(x, Wq, nullptr, nullptr, qb, Mrows, F_, F_, 0);
  gemm_f32_k<<<g256, blk, 0, stream>>>(x, Wk, nullptr, kbuf, nullptr, Mrows, F_, F_, 0);
  gemm_f32_k<<<g256, blk, 0, stream>>>(x, Wv, nullptr, vbuf, nullptr, Mrows, F_, F_, 0);
  knorm_k<<<Mrows / 4, blk, 0, stream>>>(kbuf, kb);

  gemm_f32_k<<<g256, blk, 0, stream>>>(vbuf, Wg1, bg1, tbuf, nullptr, Mrows, F_, F_, 1);
  gemm_f32_k<<<g256, blk, 0, stream>>>(tbuf, Wg2, bg2, vbuf, nullptr, Mrows, F_, F_, 0);

  float* se = tbuf;
  float* sa = tbuf + (size_t)Mrows * DQ_;
  gemm_f32_k<<<g64, blk, 0, stream>>>(x, We1, be1, se, nullptr, Mrows, DQ_, F_, 1);
  gemm_f32_k<<<g64, blk, 0, stream>>>(x, Wa1, ba1, sa, nullptr, Mrows, DQ_, F_, 1);
  etaalpha_k<<<Mrows / 4, blk, 0, stream>>>(se, sa, We2, be2, Wa2, ba2, eta, alpha);

  prep_k<<<dim3(NCH, NH_), blk, 0, stream>>>(kb, qb, eta, alpha, Tg, Gqg, Sg);

  float* yout = (float*)d_out;
  float* Mfin = yout + NTF;
  scan_chunk_k<<<dim3(16, NH_), blk, 0, stream>>>(kb, qb, vbuf, Tg, Gqg, Sg, tbuf, Mfin);

  gemm_f32_k<<<g256, blk, 0, stream>>>(tbuf, Wo, bo, tmp0, nullptr, Mrows, F_, F_, 0);
  ln_k<<<Mrows / 4, blk, 0, stream>>>(tmp0, x, gamma, beta, yout);
}

// Round 5
// 127.812 us; speedup vs baseline: 3.0732x; 1.6644x over previous
//
#include <hip/hip_runtime.h>

#define F_ 256
#define S_ 512
#define NH_ 16
#define CCH 32
#define NCH (S_/CCH)
#define KSTR 264   // bf16 row stride for [32][256] LDS tiles
#define KTSTR 36   // bf16 row stride for Kt [256][32] tile
#define TSTR 40    // bf16 row stride for 32x32-ish tiles

typedef __attribute__((ext_vector_type(8))) short short8_t;
typedef __attribute__((ext_vector_type(4))) float f32x4;

__device__ __forceinline__ float sigmoid_f(float x) { return 1.0f / (1.0f + __expf(-x)); }

__device__ __forceinline__ ushort f2bf(float x) {   // RNE float->bf16
  uint u = __float_as_uint(x);
  u += 0x7FFFu + ((u >> 16) & 1u);
  return (ushort)(u >> 16);
}

template<int CTRL>
__device__ __forceinline__ float dpp_add(float x) {
  int y = __builtin_amdgcn_update_dpp(0, __float_as_int(x), CTRL, 0xf, 0xf, true);
  return x + __int_as_float(y);
}
// butterfly sum over aligned 8-lane groups, result in all 8 lanes
__device__ __forceinline__ float red8(float x) {
  x = dpp_add<0xB1>(x);
  x = dpp_add<0x4E>(x);
  x = dpp_add<0x141>(x);
  return x;
}

// ---------- one-time: weight transpose->bf16, bias concat, x->bf16 ----------
__global__ __launch_bounds__(256) void wconv_k(
    const float* __restrict__ Wq, const float* __restrict__ Wk,
    const float* __restrict__ Wv, const float* __restrict__ Wg1,
    const float* __restrict__ Wg2, const float* __restrict__ Wo,
    const float* __restrict__ We1, const float* __restrict__ Wa1,
    const float* __restrict__ be1, const float* __restrict__ ba1,
    const float* __restrict__ x,
    ushort* __restrict__ Wt, float* __restrict__ beas,
    ushort* __restrict__ xb)
{
  const int blk = blockIdx.x, tid = threadIdx.x;
  if (blk >= 105) {   // x -> bf16
    const size_t base = (size_t)(blk - 105) * 16384;
    #pragma unroll
    for (int p = 0; p < 16; ++p) {
      const size_t o = base + (size_t)(((p << 8) + tid) << 2);
      const float4 v = *(const float4*)&x[o];
      ushort4 h4;
      h4.x = f2bf(v.x); h4.y = f2bf(v.y); h4.z = f2bf(v.z); h4.w = f2bf(v.w);
      *(ushort4*)&xb[o] = h4;
    }
    return;
  }
  if (blk == 104) {
    if (tid < 64) beas[tid] = be1[tid];
    else if (tid < 128) beas[tid] = ba1[tid - 64];
    return;
  }
  __shared__ float tile[64][65];
  const float* src; int N, k0, n0; size_t dstbase;
  if (blk < 96) {
    const int w = blk >> 4, tl = blk & 15;
    const float* ws_[6] = {Wq, Wk, Wv, Wg1, Wg2, Wo};
    src = ws_[w]; N = 256;
    k0 = (tl >> 2) * 64; n0 = (tl & 3) * 64;
    dstbase = (size_t)w * 65536;
  } else {
    const int w = (blk - 96) >> 2, tl = (blk - 96) & 3;
    src = w ? Wa1 : We1; N = 64;
    k0 = tl * 64; n0 = 0;
    dstbase = 6 * 65536 + (size_t)w * (64 * 256);
  }
  #pragma unroll
  for (int p = 0; p < 4; ++p) {
    const int idx = (p << 8) + tid;
    const int r = idx >> 4, c4 = (idx & 15) << 2;
    const float4 v = *(const float4*)&src[(size_t)(k0 + r) * N + n0 + c4];
    tile[r][c4 + 0] = v.x; tile[r][c4 + 1] = v.y;
    tile[r][c4 + 2] = v.z; tile[r][c4 + 3] = v.w;
  }
  __syncthreads();
  #pragma unroll
  for (int p = 0; p < 4; ++p) {
    const int idx = (p << 8) + tid;
    const int nl = idx >> 4, kc = (idx & 15) << 2;
    ushort4 o;
    o.x = f2bf(tile[kc + 0][nl]); o.y = f2bf(tile[kc + 1][nl]);
    o.z = f2bf(tile[kc + 2][nl]); o.w = f2bf(tile[kc + 3][nl]);
    *(ushort4*)&Wt[dstbase + (size_t)(n0 + nl) * 256 + k0 + kc] = o;
  }
}

// ---------- bf16 MFMA GEMM: C = act(A @ W + bias) ----------
// A: [M][K] bf16 row-major; Wt: [N][K] bf16 (pre-transposed). BM=BN=BK=64.
// 4 waves 2x2; wave computes 32x32 (2x2 fragments of 16x16).
__global__ __launch_bounds__(256) void gemm_bf16_k(
    const ushort* __restrict__ A, const ushort* __restrict__ Wt,
    const float* __restrict__ bias, float* __restrict__ Cf,
    ushort* __restrict__ Cb, int N, int K, int act)
{
  __shared__ ushort As[64 * 72];
  __shared__ ushort Ws[64 * 72];
  const int tid = threadIdx.x;
  const int wv = tid >> 6, l = tid & 63;
  const int ln = l & 15, hi = l >> 4, hi4 = hi << 2, hi8 = hi << 3;
  const int wr = wv >> 1, wc = wv & 1;
  const int row0 = blockIdx.y * 64, col0 = blockIdx.x * 64;

  f32x4 acc[2][2];
  #pragma unroll
  for (int i = 0; i < 2; ++i)
    #pragma unroll
    for (int j = 0; j < 2; ++j)
      #pragma unroll
      for (int r = 0; r < 4; ++r) acc[i][j][r] = 0.f;

  for (int k0 = 0; k0 < K; k0 += 64) {
    #pragma unroll
    for (int p = 0; p < 2; ++p) {
      const int idx = (p << 8) + tid;
      const int r = idx >> 3, c8 = (idx & 7) << 3;
      *(short8_t*)&As[r * 72 + c8] = *(const short8_t*)&A[(size_t)(row0 + r) * K + k0 + c8];
      *(short8_t*)&Ws[r * 72 + c8] = *(const short8_t*)&Wt[(size_t)(col0 + r) * K + k0 + c8];
    }
    __syncthreads();
    #pragma unroll
    for (int kk = 0; kk < 2; ++kk) {
      short8_t a0 = *(const short8_t*)&As[(wr * 32 + ln) * 72 + kk * 32 + hi8];
      short8_t a1 = *(const short8_t*)&As[(wr * 32 + 16 + ln) * 72 + kk * 32 + hi8];
      short8_t b0 = *(const short8_t*)&Ws[(wc * 32 + ln) * 72 + kk * 32 + hi8];
      short8_t b1 = *(const short8_t*)&Ws[(wc * 32 + 16 + ln) * 72 + kk * 32 + hi8];
      acc[0][0] = __builtin_amdgcn_mfma_f32_16x16x32_bf16(a0, b0, acc[0][0], 0, 0, 0);
      acc[0][1] = __builtin_amdgcn_mfma_f32_16x16x32_bf16(a0, b1, acc[0][1], 0, 0, 0);
      acc[1][0] = __builtin_amdgcn_mfma_f32_16x16x32_bf16(a1, b0, acc[1][0], 0, 0, 0);
      acc[1][1] = __builtin_amdgcn_mfma_f32_16x16x32_bf16(a1, b1, acc[1][1], 0, 0, 0);
    }
    __syncthreads();
  }

  #pragma unroll
  for (int mi = 0; mi < 2; ++mi)
    #pragma unroll
    for (int ni = 0; ni < 2; ++ni) {
      const int col = col0 + wc * 32 + ni * 16 + ln;
      const float bval = bias ? bias[col] : 0.f;
      #pragma unroll
      for (int r = 0; r < 4; ++r) {
        const int row = row0 + wr * 32 + mi * 16 + hi4 + r;
        float vx = acc[mi][ni][r] + bval;
        if (act == 1) vx = vx * sigmoid_f(vx);
        if (Cf) Cf[(size_t)row * N + col] = vx;
        if (Cb) Cb[(size_t)row * N + col] = f2bf(vx);
      }
    }
}

// k-row L2 normalize (fp32 in), output bf16
__global__ __launch_bounds__(256) void knorm_k(const float* __restrict__ k,
                                               ushort* __restrict__ kb)
{
  const int lane = threadIdx.x & 63;
  const size_t row = ((size_t)blockIdx.x << 2) + (threadIdx.x >> 6);
  const size_t off = row * F_ + ((size_t)lane << 2);
  float4 v = *(const float4*)&k[off];
  float ss = v.x * v.x + v.y * v.y + v.z * v.z + v.w * v.w;
  #pragma unroll
  for (int m = 1; m < 64; m <<= 1) ss += __shfl_xor(ss, m, 64);
  const float sc = 1.0f / fmaxf(sqrtf(ss), 1e-12f);
  ushort4 o;
  o.x = f2bf(v.x * sc); o.y = f2bf(v.y * sc);
  o.z = f2bf(v.z * sc); o.w = f2bf(v.w * sc);
  *(ushort4*)&kb[off] = o;
}

// sesa: [row][128] fp32 (cols 0..63 = silu e-branch, 64..127 = silu a-branch)
__global__ __launch_bounds__(256) void etaalpha_k(
    const float* __restrict__ sesa,
    const float* __restrict__ We2, const float* __restrict__ be2,
    const float* __restrict__ Wa2, const float* __restrict__ ba2,
    float* __restrict__ eta, float* __restrict__ alpha)
{
  const int lane = threadIdx.x & 63;
  const size_t row = ((size_t)blockIdx.x << 2) + (threadIdx.x >> 6);
  float pe = sesa[row * 128 + lane] * We2[lane];
  float pa = sesa[row * 128 + 64 + lane] * Wa2[lane];
  #pragma unroll
  for (int m = 1; m < 64; m <<= 1) {
    pe += __shfl_xor(pe, m, 64);
    pa += __shfl_xor(pa, m, 64);
  }
  if (lane == 0) {
    eta[row]   = sigmoid_f(pe + be2[0]) * 0.1f + 0.01f;
    alpha[row] = sigmoid_f(pa + ba2[0]) * 0.5f + 0.5f;
  }
}

__global__ __launch_bounds__(256) void ln_k(
    const float* __restrict__ t, const float* __restrict__ x,
    const float* __restrict__ gamma, const float* __restrict__ beta,
    float* __restrict__ y)
{
  const int lane = threadIdx.x & 63;
  const size_t row = ((size_t)blockIdx.x << 2) + (threadIdx.x >> 6);
  const size_t off = row * F_ + ((size_t)lane << 2);
  const float4 tv = *(const float4*)&t[off];
  const float4 xv = *(const float4*)&x[off];
  float4 v = make_float4(tv.x + xv.x, tv.y + xv.y, tv.z + xv.z, tv.w + xv.w);
  float sm = v.x + v.y + v.z + v.w;
  float sq = v.x * v.x + v.y * v.y + v.z * v.z + v.w * v.w;
  #pragma unroll
  for (int m = 1; m < 64; m <<= 1) {
    sm += __shfl_xor(sm, m, 64);
    sq += __shfl_xor(sq, m, 64);
  }
  const float mu  = sm * (1.0f / 256.0f);
  const float var = sq * (1.0f / 256.0f) - mu * mu;
  const float rstd = rsqrtf(var + 1e-5f);
  const float4 g = *(const float4*)&gamma[(size_t)lane << 2];
  const float4 b = *(const float4*)&beta[(size_t)lane << 2];
  float4 o;
  o.x = (v.x - mu) * rstd * g.x + b.x;
  o.y = (v.y - mu) * rstd * g.y + b.y;
  o.z = (v.z - mu) * rstd * g.z + b.z;
  o.w = (v.w - mu) * rstd * g.w + b.w;
  *(float4*)&y[off] = o;
}

// ---- prep: per (chunk, head): G=KK^T, masked Gq=QK^T, decay scalars,
// T = (I + strictlower(diag(b) G))^{-1}, and transposed-K global copy.
__global__ __launch_bounds__(256) void prep_k(
    const ushort* __restrict__ kb, const ushort* __restrict__ qb,
    const float* __restrict__ eta, const float* __restrict__ alpha,
    ushort* __restrict__ Tg, ushort* __restrict__ Gqg, float* __restrict__ Sg,
    ushort* __restrict__ Ktg)
{
  __shared__ ushort K_lds[CCH * KSTR];
  __shared__ ushort Q_lds[CCH * KSTR];
  __shared__ float  G_lds[CCH * CCH];
  __shared__ float  ea[2 * CCH];
  __shared__ float  scal[100];

  const int tid = threadIdx.x;
  const int ch = blockIdx.x, h = blockIdx.y;
  const int t0 = ch * CCH;
  const int l = tid & 63, wv = tid >> 6;
  const int ln = l & 15, hi = l >> 4;
  const int hi8 = hi * 8, hi4 = hi * 4;

  const ushort* kg = kb + (size_t)(h * S_ + t0) * F_;
  const ushort* qg = qb + (size_t)(h * S_ + t0) * F_;
  #pragma unroll
  for (int w = 0; w < 4; ++w) {
    int o = w * 256 + tid; int t = o >> 5, c8 = (o & 31) << 3;
    *(short8_t*)&K_lds[t * KSTR + c8] = *(const short8_t*)&kg[(size_t)t * F_ + c8];
    *(short8_t*)&Q_lds[t * KSTR + c8] = *(const short8_t*)&qg[(size_t)t * F_ + c8];
  }
  if (tid < CCH)            ea[tid] = eta[(size_t)h * S_ + t0 + tid];
  else if (tid < 2 * CCH)   ea[tid] = alpha[(size_t)h * S_ + t0 + tid - CCH];
  __syncthreads();

  // transposed K copy: Ktg[h][c][t]
  {
    const int tt = tid & 31, cl = tid >> 5;
    for (int cp = 0; cp < 32; ++cp) {
      const int c = cp * 8 + cl;
      Ktg[((size_t)h * F_ + c) * S_ + t0 + tt] = K_lds[tt * KSTR + c];
    }
  }

  {
    const int tI = wv >> 1, tJ = wv & 1;
    f32x4 accG = {0.f, 0.f, 0.f, 0.f};
    f32x4 accQ = {0.f, 0.f, 0.f, 0.f};
    #pragma unroll
    for (int ko = 0; ko < 8; ++ko) {
      const int cb = ko * 32 + hi8;
      short8_t bfr = *(const short8_t*)&K_lds[(tJ * 16 + ln) * KSTR + cb];
      short8_t aK  = *(const short8_t*)&K_lds[(tI * 16 + ln) * KSTR + cb];
      short8_t aQ  = *(const short8_t*)&Q_lds[(tI * 16 + ln) * KSTR + cb];
      accG = __builtin_amdgcn_mfma_f32_16x16x32_bf16(aK, bfr, accG, 0, 0, 0);
      accQ = __builtin_amdgcn_mfma_f32_16x16x32_bf16(aQ, bfr, accQ, 0, 0, 0);
    }
    ushort* Gqo = Gqg + (size_t)(h * NCH + ch) * (CCH * CCH);
    #pragma unroll
    for (int r = 0; r < 4; ++r) {
      const int t = tI * 16 + hi4 + r, s = tJ * 16 + ln;
      G_lds[t * CCH + s] = accG[r];
      Gqo[t * CCH + s] = (s < t) ? f2bf(accQ[r]) : (ushort)0;
    }
  }
  if (tid == 0) {
    float gp = 1.f;
    for (int t = 0; t < CCH; ++t) {
      const float a = ea[CCH + t], e = ea[t];
      const float gm = gp * a;
      scal[t]           = e / a;    // b_t
      scal[CCH + t]     = e / gm;   // c_t
      scal[2 * CCH + t] = gp;       // gamma_prev
      gp = gm;
    }
    scal[3 * CCH] = gp;             // gamma_C
  }
  __syncthreads();

  // forward substitution: column j of T
  {
    const int j = tid >> 3, g = tid & 7;
    float x0 = 0.f, x1 = 0.f, x2 = 0.f, x3 = 0.f;
    ushort* To = Tg + (size_t)(h * NCH + ch) * (CCH * CCH);
    #pragma unroll
    for (int t = 0; t < CCH; ++t) {
      float p = 0.f;
      const f32x4 gr = *(const f32x4*)&G_lds[t * CCH + 4 * g];
      if (4 * g + 0 < t) p += gr[0] * x0;
      if (4 * g + 1 < t) p += gr[1] * x1;
      if (4 * g + 2 < t) p += gr[2] * x2;
      if (4 * g + 3 < t) p += gr[3] * x3;
      const float tot = red8(p);
      const float xt = ((t == j) ? 1.f : 0.f) - scal[t] * tot;
      if (g == (t >> 2)) {
        if ((t & 3) == 0) x0 = xt; else if ((t & 3) == 1) x1 = xt;
        else if ((t & 3) == 2) x2 = xt; else x3 = xt;
      }
      if (g == 0) To[t * CCH + j] = f2bf(xt);
    }
  }
  if (tid < 97) Sg[(size_t)(h * NCH + ch) * 128 + tid] = scal[tid];
}

// ---- chunked scan, double-buffered + prefetch + XCD-aware block remap.
__global__ __launch_bounds__(256, 1) void scan_chunk_k(
    const ushort* __restrict__ kb, const ushort* __restrict__ qb,
    const float* __restrict__ vh, const ushort* __restrict__ Ktg,
    const ushort* __restrict__ Tg, const ushort* __restrict__ Gqg,
    const float* __restrict__ Sg,
    ushort* __restrict__ outb, float* __restrict__ Mout)
{
  __shared__ ushort K_lds[2][CCH * KSTR];
  __shared__ ushort Q_lds[2][CCH * KSTR];
  __shared__ ushort Kt_lds[2][F_ * KTSTR];
  __shared__ ushort M_lds[16 * KSTR];
  __shared__ ushort T_lds[2][CCH * TSTR];
  __shared__ ushort Gq_lds[2][CCH * TSTR];
  __shared__ ushort Wt_lds[16 * TSTR];
  __shared__ ushort R_lds[16 * TSTR];
  __shared__ float  QM_lds[CCH * 20];
  __shared__ float  V_lds[2][CCH * 16];
  __shared__ float  scal[2][104];

  const int tid = threadIdx.x;
  // XCD-aware remap: flat%8 = XCD (heuristic); give each XCD 2 heads x 16 slices
  const int flat = blockIdx.x;
  const int h = (flat & 7) + (((flat >> 3) >> 4) << 3);
  const int slice = (flat >> 3) & 15;
  const int r0 = slice * 16;
  const int wv = tid >> 6, l = tid & 63;
  const int ln = l & 15, hi = l >> 4, hi4 = hi << 2, hi8 = hi << 3;

  for (int u = tid; u < 16 * KSTR / 8; u += 256) {
    short8_t z = {0, 0, 0, 0, 0, 0, 0, 0};
    *(short8_t*)&M_lds[u * 8] = z;
  }
  f32x4 Mf[4];
  #pragma unroll
  for (int q = 0; q < 4; ++q)
    #pragma unroll
    for (int r = 0; r < 4; ++r) Mf[q][r] = 0.f;

  const ushort* kgh = kb + (size_t)h * S_ * F_;
  const ushort* qgh = qb + (size_t)h * S_ * F_;
  const ushort* kth = Ktg + (size_t)h * F_ * S_;

  short8_t pK[4], pQ[4], pKt[4], pTG;
  float pV[2], pS = 0.f;

  auto loadchunk = [&](int ch) {
    const int t0 = ch * CCH;
    #pragma unroll
    for (int r = 0; r < 4; ++r) {
      const int idx = (r << 8) + tid;
      const int t = idx >> 5, c8 = (idx & 31) << 3;
      pK[r] = *(const short8_t*)&kgh[(size_t)(t0 + t) * F_ + c8];
      pQ[r] = *(const short8_t*)&qgh[(size_t)(t0 + t) * F_ + c8];
    }
    #pragma unroll
    for (int r = 0; r < 4; ++r) {
      const int idx = (r << 8) + tid;
      const int c = idx >> 2, t8 = (idx & 3) << 3;
      pKt[r] = *(const short8_t*)&kth[(size_t)c * S_ + t0 + t8];
    }
    #pragma unroll
    for (int u = 0; u < 2; ++u) {
      const int e = (u << 8) + tid, t = e >> 4, i = e & 15;
      pV[u] = vh[(size_t)(h * S_ + t0 + t) * F_ + r0 + i];
    }
    {
      const ushort* Ti = Tg  + (size_t)(h * NCH + ch) * (CCH * CCH);
      const ushort* Gi = Gqg + (size_t)(h * NCH + ch) * (CCH * CCH);
      if (tid < 128) {
        const int t = tid >> 2, c8 = (tid & 3) << 3;
        pTG = *(const short8_t*)&Ti[t * CCH + c8];
      } else {
        const int t = (tid - 128) >> 2, c8 = ((tid - 128) & 3) << 3;
        pTG = *(const short8_t*)&Gi[t * CCH + c8];
      }
    }
    if (tid < 97) pS = Sg[(size_t)(h * NCH + ch) * 128 + tid];
  };

  auto commit = [&](int buf) {
    #pragma unroll
    for (int r = 0; r < 4; ++r) {
      const int idx = (r << 8) + tid;
      const int t = idx >> 5, c8 = (idx & 31) << 3;
      *(short8_t*)&K_lds[buf][t * KSTR + c8] = pK[r];
      *(short8_t*)&Q_lds[buf][t * KSTR + c8] = pQ[r];
    }
    #pragma unroll
    for (int r = 0; r < 4; ++r) {
      const int idx = (r << 8) + tid;
      const int c = idx >> 2, t8 = (idx & 3) << 3;
      *(short8_t*)&Kt_lds[buf][c * KTSTR + t8] = pKt[r];
    }
    #pragma unroll
    for (int u = 0; u < 2; ++u) V_lds[buf][(u << 8) + tid] = pV[u];
    if (tid < 128) {
      const int t = tid >> 2, c8 = (tid & 3) << 3;
      *(short8_t*)&T_lds[buf][t * TSTR + c8] = pTG;
    } else {
      const int t = (tid - 128) >> 2, c8 = ((tid - 128) & 3) << 3;
      *(short8_t*)&Gq_lds[buf][t * TSTR + c8] = pTG;
    }
    if (tid < 97) scal[buf][tid] = pS;
  };

  loadchunk(0);
  commit(0);
  __syncthreads();

  for (int ch = 0; ch < NCH; ++ch) {
    const int buf = ch & 1;
    const int t0 = ch * CCH;
    if (ch + 1 < NCH) loadchunk(ch + 1);

    // phase 2: KM->RHS (waves 0,1) || QM (waves 2,3)
    if (wv < 2) {
      const int I = wv;
      f32x4 acc = {0.f, 0.f, 0.f, 0.f};
      #pragma unroll
      for (int ko = 0; ko < 8; ++ko) {
        short8_t a = *(const short8_t*)&K_lds[buf][(I * 16 + ln) * KSTR + ko * 32 + hi8];
        short8_t b = *(const short8_t*)&M_lds[ln * KSTR + ko * 32 + hi8];
        acc = __builtin_amdgcn_mfma_f32_16x16x32_bf16(a, b, acc, 0, 0, 0);
      }
      #pragma unroll
      for (int r = 0; r < 4; ++r) {
        const int t = I * 16 + hi4 + r;
        const float rhs = scal[buf][CCH + t] * V_lds[buf][t * 16 + ln]
                        - scal[buf][t] * acc[r];
        R_lds[ln * TSTR + t] = f2bf(rhs);
      }
    } else {
      const int I = wv - 2;
      f32x4 acc = {0.f, 0.f, 0.f, 0.f};
      #pragma unroll
      for (int ko = 0; ko < 8; ++ko) {
        short8_t a = *(const short8_t*)&Q_lds[buf][(I * 16 + ln) * KSTR + ko * 32 + hi8];
        short8_t b = *(const short8_t*)&M_lds[ln * KSTR + ko * 32 + hi8];
        acc = __builtin_amdgcn_mfma_f32_16x16x32_bf16(a, b, acc, 0, 0, 0);
      }
      #pragma unroll
      for (int r = 0; r < 4; ++r)
        QM_lds[(I * 16 + hi4 + r) * 20 + ln] = acc[r];
    }
    __syncthreads();

    // phase 3: W = T @ RHS (waves 0,1), stored [c][t]
    if (wv < 2) {
      const int I = wv;
      short8_t a = *(const short8_t*)&T_lds[buf][(I * 16 + ln) * TSTR + hi8];
      short8_t b = *(const short8_t*)&R_lds[ln * TSTR + hi8];
      f32x4 z = {0.f, 0.f, 0.f, 0.f};
      f32x4 d = __builtin_amdgcn_mfma_f32_16x16x32_bf16(a, b, z, 0, 0, 0);
      #pragma unroll
      for (int r = 0; r < 4; ++r)
        Wt_lds[ln * TSTR + I * 16 + hi4 + r] = f2bf(d[r]);
    }
    __syncthreads();

    // phase 4: OUT (waves 0,1) || M update (all waves)
    if (wv < 2) {
      const int I = wv;
      short8_t a = *(const short8_t*)&Gq_lds[buf][(I * 16 + ln) * TSTR + hi8];
      short8_t b = *(const short8_t*)&Wt_lds[ln * TSTR + hi8];
      f32x4 z = {0.f, 0.f, 0.f, 0.f};
      f32x4 d = __builtin_amdgcn_mfma_f32_16x16x32_bf16(a, b, z, 0, 0, 0);
      #pragma unroll
      for (int r = 0; r < 4; ++r) {
        const int t = I * 16 + hi4 + r;
        outb[(size_t)(h * S_ + t0 + t) * F_ + r0 + ln] =
            f2bf(scal[buf][2 * CCH + t] * (QM_lds[t * 20 + ln] + d[r]));
      }
    }
    {
      const float gC = scal[buf][3 * CCH];
      short8_t aw = *(const short8_t*)&Wt_lds[ln * TSTR + hi8];
      #pragma unroll
      for (int qq = 0; qq < 4; ++qq) {
        const int jt = wv * 4 + qq;
        short8_t bk = *(const short8_t*)&Kt_lds[buf][(jt * 16 + ln) * KTSTR + hi8];
        f32x4 d = __builtin_amdgcn_mfma_f32_16x16x32_bf16(aw, bk, Mf[qq], 0, 0, 0);
        #pragma unroll
        for (int r = 0; r < 4; ++r) {
          const float nv = gC * d[r];
          Mf[qq][r] = nv;
          M_lds[(hi4 + r) * KSTR + jt * 16 + ln] = f2bf(nv);
        }
      }
    }
    if (ch + 1 < NCH) commit(buf ^ 1);
    __syncthreads();
  }

  #pragma unroll
  for (int qq = 0; qq < 4; ++qq) {
    const int jt = wv * 4 + qq;
    #pragma unroll
    for (int r = 0; r < 4; ++r)
      Mout[((size_t)h * F_ + r0 + hi4 + r) * F_ + jt * 16 + ln] = Mf[qq][r];
  }
}

extern "C" void kernel_launch(void* const* d_in, const int* in_sizes, int n_in,
                              void* d_out, int out_size, void* d_ws, size_t ws_size,
                              hipStream_t stream)
{
  const float* x    = (const float*)d_in[0];
  const float* Wq   = (const float*)d_in[1];
  const float* Wk   = (const float*)d_in[2];
  const float* Wv   = (const float*)d_in[3];
  const float* Wg1  = (const float*)d_in[4];
  const float* bg1  = (const float*)d_in[5];
  const float* Wg2  = (const float*)d_in[6];
  const float* bg2  = (const float*)d_in[7];
  const float* We1  = (const float*)d_in[8];
  const float* be1  = (const float*)d_in[9];
  const float* We2  = (const float*)d_in[10];
  const float* be2  = (const float*)d_in[11];
  const float* Wa1  = (const float*)d_in[12];
  const float* ba1  = (const float*)d_in[13];
  const float* Wa2  = (const float*)d_in[14];
  const float* ba2  = (const float*)d_in[15];
  const float* Wo   = (const float*)d_in[16];
  const float* bo   = (const float*)d_in[17];
  const float* gamma= (const float*)d_in[18];
  const float* beta = (const float*)d_in[19];

  const int Mrows = NH_ * S_;               // 8192
  const size_t MM = 1048576;                // 1M floats
  const size_t NTF = 2 * MM;                // elements per [8192][256] tensor

  float* ws = (float*)d_ws;
  // layout (float offsets):
  ushort* xb   = (ushort*)(ws + 0 * MM);        // bf16 x          [0,1M)
  ushort* qb   = (ushort*)(ws + 1 * MM);        // bf16 q          [1M,2M)
  ushort* kb   = (ushort*)(ws + 2 * MM);        // bf16 kn         [2M,3M)
  ushort* vb   = (ushort*)(ws + 3 * MM);        // bf16 v          [3M,4M)
  ushort* Tg   = (ushort*)(ws + 3 * MM);        // reuse vb after g1
  ushort* Gqg  = Tg + 262144;
  float*  Sg   = ws + 3 * MM + 262144;
  ushort* t1b  = (ushort*)(ws + 4 * MM);        // bf16 t1         [4M,5M)
  ushort* outb = (ushort*)(ws + 4 * MM);        // reuse after g2
  float*  kf   = ws + 5 * MM;                   // f32 k           [5M,7M)
  float*  vhat = ws + 5 * MM;                   // reuse after knorm
  float*  sesa = ws + 7 * MM;                   // f32 [8192][128] [7M,8M)
  float*  eta  = ws + 8 * MM;
  float*  alpha= eta + Mrows;
  ushort* Ktg  = (ushort*)(ws + 8 * MM + 16384);          // bf16 [16][256][512]
  ushort* Wt   = (ushort*)(ws + 9 * MM + 16384);          // transposed weights
  float*  beas = ws + 9 * MM + 16384 + 212992;            // fused bias[128]
  float*  ytmp = ws + 0 * MM;                   // reuse xb+qb after scan

  dim3 blk(256);
  dim3 g256(4, 128);   // N=256 GEMMs
  dim3 g128(2, 128);   // N=128 GEMM

  wconv_k<<<233, blk, 0, stream>>>(Wq, Wk, Wv, Wg1, Wg2, Wo, We1, Wa1,
                                   be1, ba1, x, Wt, beas, xb);

  gemm_bf16_k<<<g256, blk, 0, stream>>>(xb, Wt + 0 * 65536, nullptr, nullptr, qb, 256, 256, 0);
  gemm_bf16_k<<<g256, blk, 0, stream>>>(xb, Wt + 1 * 65536, nullptr, kf, nullptr, 256, 256, 0);
  gemm_bf16_k<<<g256, blk, 0, stream>>>(xb, Wt + 2 * 65536, nullptr, nullptr, vb, 256, 256, 0);
  knorm_k<<<Mrows / 4, blk, 0, stream>>>(kf, kb);

  gemm_bf16_k<<<g256, blk, 0, stream>>>(vb, Wt + 3 * 65536, bg1, nullptr, t1b, 256, 256, 1);
  gemm_bf16_k<<<g256, blk, 0, stream>>>(t1b, Wt + 4 * 65536, bg2, vhat, nullptr, 256, 256, 0);

  gemm_bf16_k<<<g128, blk, 0, stream>>>(xb, Wt + 6 * 65536, beas, sesa, nullptr, 128, 256, 1);
  etaalpha_k<<<Mrows / 4, blk, 0, stream>>>(sesa, We2, be2, Wa2, ba2, eta, alpha);

  prep_k<<<dim3(NCH, NH_), blk, 0, stream>>>(kb, qb, eta, alpha, Tg, Gqg, Sg, Ktg);

  float* yout = (float*)d_out;
  float* Mfin = yout + NTF;
  scan_chunk_k<<<256, blk, 0, stream>>>(kb, qb, vhat, Ktg, Tg, Gqg, Sg, outb, Mfin);

  gemm_bf16_k<<<g256, blk, 0, stream>>>(outb, Wt + 5 * 65536, bo, ytmp, nullptr, 256, 256, 0);
  ln_k<<<Mrows / 4, blk, 0, stream>>>(ytmp, x, gamma, beta, yout);
}

// Round 6
// 101.212 us; speedup vs baseline: 3.8809x; 1.2628x over previous
//
#include <hip/hip_runtime.h>

#define F_ 256
#define S_ 512
#define NH_ 16
#define CCH 32
#define NCH (S_/CCH)
#define KSTR 264   // bf16 row stride for [32][256] LDS tiles
#define KTSTR 36   // bf16 row stride for Kt [256][32] tile
#define TSTR 40    // bf16 row stride for 32x32-ish tiles
#define PSTR 17    // f32 padded stride for [32][16] partial tiles

typedef __attribute__((ext_vector_type(8))) short short8_t;
typedef __attribute__((ext_vector_type(4))) float f32x4;

__device__ __forceinline__ float sigmoid_f(float x) { return 1.0f / (1.0f + __expf(-x)); }

__device__ __forceinline__ ushort f2bf(float x) {   // RNE float->bf16
  uint u = __float_as_uint(x);
  u += 0x7FFFu + ((u >> 16) & 1u);
  return (ushort)(u >> 16);
}
__device__ __forceinline__ float bf2f(ushort u) {
  return __uint_as_float((uint)u << 16);
}

template<int CTRL>
__device__ __forceinline__ float dpp_add(float x) {
  int y = __builtin_amdgcn_update_dpp(0, __float_as_int(x), CTRL, 0xf, 0xf, true);
  return x + __int_as_float(y);
}
// butterfly sum over aligned 8-lane groups, result in all 8 lanes
__device__ __forceinline__ float red8(float x) {
  x = dpp_add<0xB1>(x);
  x = dpp_add<0x4E>(x);
  x = dpp_add<0x141>(x);
  return x;
}

// ---------- one-time: weight transpose->bf16, bias concat, x->bf16 ----------
// Wt row layout (ushort offsets): q=0 k=65536 v=131072 e1=196608 a1=212992
//                                 g1=229376 g2=294912 o=360448
__global__ __launch_bounds__(256) void wconv_k(
    const float* __restrict__ Wq, const float* __restrict__ Wk,
    const float* __restrict__ Wv, const float* __restrict__ Wg1,
    const float* __restrict__ Wg2, const float* __restrict__ Wo,
    const float* __restrict__ We1, const float* __restrict__ Wa1,
    const float* __restrict__ be1, const float* __restrict__ ba1,
    const float* __restrict__ x,
    ushort* __restrict__ Wt, float* __restrict__ beas,
    ushort* __restrict__ xb)
{
  const int blk = blockIdx.x, tid = threadIdx.x;
  if (blk >= 105) {   // x -> bf16
    const size_t base = (size_t)(blk - 105) * 16384;
    #pragma unroll
    for (int p = 0; p < 16; ++p) {
      const size_t o = base + (size_t)(((p << 8) + tid) << 2);
      const float4 v = *(const float4*)&x[o];
      ushort4 h4;
      h4.x = f2bf(v.x); h4.y = f2bf(v.y); h4.z = f2bf(v.z); h4.w = f2bf(v.w);
      *(ushort4*)&xb[o] = h4;
    }
    return;
  }
  if (blk == 104) {
    if (tid < 64) beas[tid] = be1[tid];
    else if (tid < 128) beas[tid] = ba1[tid - 64];
    return;
  }
  __shared__ float tile[64][65];
  const float* src; int N, k0, n0; size_t dstbase;
  if (blk < 96) {
    const int w = blk >> 4, tl = blk & 15;
    const float* ws_[6] = {Wq, Wk, Wv, Wg1, Wg2, Wo};
    const size_t dstb[6] = {0, 65536, 131072, 229376, 294912, 360448};
    src = ws_[w]; N = 256;
    k0 = (tl >> 2) * 64; n0 = (tl & 3) * 64;
    dstbase = dstb[w];
  } else {
    const int w = (blk - 96) >> 2, tl = (blk - 96) & 3;
    src = w ? Wa1 : We1; N = 64;
    k0 = tl * 64; n0 = 0;
    dstbase = w ? 212992 : 196608;
  }
  #pragma unroll
  for (int p = 0; p < 4; ++p) {
    const int idx = (p << 8) + tid;
    const int r = idx >> 4, c4 = (idx & 15) << 2;
    if (c4 < N) {
      const float4 v = *(const float4*)&src[(size_t)(k0 + r) * N + n0 + c4];
      tile[r][c4 + 0] = v.x; tile[r][c4 + 1] = v.y;
      tile[r][c4 + 2] = v.z; tile[r][c4 + 3] = v.w;
    }
  }
  __syncthreads();
  #pragma unroll
  for (int p = 0; p < 4; ++p) {
    const int idx = (p << 8) + tid;
    const int nl = idx >> 4, kc = (idx & 15) << 2;
    if (nl < ((blk < 96) ? 64 : 64) && (n0 + nl) < ((blk < 96) ? 256 : 64)) {
      ushort4 o;
      o.x = f2bf(tile[kc + 0][nl]); o.y = f2bf(tile[kc + 1][nl]);
      o.z = f2bf(tile[kc + 2][nl]); o.w = f2bf(tile[kc + 3][nl]);
      *(ushort4*)&Wt[dstbase + (size_t)(n0 + nl) * 256 + k0 + kc] = o;
    }
  }
}

// ---------- fused QKVE GEMM: out = xb @ [Wq|Wk|Wv|We1|Wa1] (N=896, K=256) ----
__global__ __launch_bounds__(256) void qkve_k(
    const ushort* __restrict__ A, const ushort* __restrict__ Wt,
    const float* __restrict__ beas,
    ushort* __restrict__ qb, float* __restrict__ kf,
    ushort* __restrict__ vb, float* __restrict__ sesa)
{
  __shared__ ushort As[2][64 * 72];
  __shared__ ushort Ws[2][64 * 72];
  const int tid = threadIdx.x;
  const int wv = tid >> 6, l = tid & 63;
  const int ln = l & 15, hi = l >> 4, hi4 = hi << 2, hi8 = hi << 3;
  const int wr = wv >> 1, wc = wv & 1;
  const int row0 = blockIdx.y * 64, col0 = blockIdx.x * 64;
  const int r_ = tid >> 3, c8_ = (tid & 7) << 3;

  short8_t pA[2], pB[2];
  auto loadT = [&](int k0) {
    pA[0] = *(const short8_t*)&A[(size_t)(row0 + r_) * 256 + k0 + c8_];
    pA[1] = *(const short8_t*)&A[(size_t)(row0 + 32 + r_) * 256 + k0 + c8_];
    pB[0] = *(const short8_t*)&Wt[(size_t)(col0 + r_) * 256 + k0 + c8_];
    pB[1] = *(const short8_t*)&Wt[(size_t)(col0 + 32 + r_) * 256 + k0 + c8_];
  };
  auto commitT = [&](int b) {
    *(short8_t*)&As[b][r_ * 72 + c8_] = pA[0];
    *(short8_t*)&As[b][(32 + r_) * 72 + c8_] = pA[1];
    *(short8_t*)&Ws[b][r_ * 72 + c8_] = pB[0];
    *(short8_t*)&Ws[b][(32 + r_) * 72 + c8_] = pB[1];
  };

  f32x4 acc[2][2];
  #pragma unroll
  for (int i = 0; i < 2; ++i)
    #pragma unroll
    for (int j = 0; j < 2; ++j)
      #pragma unroll
      for (int r = 0; r < 4; ++r) acc[i][j][r] = 0.f;

  loadT(0); commitT(0); __syncthreads();
  #pragma unroll
  for (int t = 0; t < 4; ++t) {
    const int b = t & 1;
    if (t < 3) loadT((t + 1) << 6);
    #pragma unroll
    for (int kk = 0; kk < 2; ++kk) {
      short8_t a0 = *(const short8_t*)&As[b][(wr * 32 + ln) * 72 + kk * 32 + hi8];
      short8_t a1 = *(const short8_t*)&As[b][(wr * 32 + 16 + ln) * 72 + kk * 32 + hi8];
      short8_t b0 = *(const short8_t*)&Ws[b][(wc * 32 + ln) * 72 + kk * 32 + hi8];
      short8_t b1 = *(const short8_t*)&Ws[b][(wc * 32 + 16 + ln) * 72 + kk * 32 + hi8];
      acc[0][0] = __builtin_amdgcn_mfma_f32_16x16x32_bf16(a0, b0, acc[0][0], 0, 0, 0);
      acc[0][1] = __builtin_amdgcn_mfma_f32_16x16x32_bf16(a0, b1, acc[0][1], 0, 0, 0);
      acc[1][0] = __builtin_amdgcn_mfma_f32_16x16x32_bf16(a1, b0, acc[1][0], 0, 0, 0);
      acc[1][1] = __builtin_amdgcn_mfma_f32_16x16x32_bf16(a1, b1, acc[1][1], 0, 0, 0);
    }
    if (t < 3) commitT(b ^ 1);
    __syncthreads();
  }

  #pragma unroll
  for (int mi = 0; mi < 2; ++mi)
    #pragma unroll
    for (int ni = 0; ni < 2; ++ni) {
      const int col = col0 + wc * 32 + ni * 16 + ln;
      #pragma unroll
      for (int r = 0; r < 4; ++r) {
        const int row = row0 + wr * 32 + mi * 16 + hi4 + r;
        float vx = acc[mi][ni][r];
        if (col0 < 256)      qb[(size_t)row * 256 + col] = f2bf(vx);
        else if (col0 < 512) kf[(size_t)row * 256 + (col - 256)] = vx;
        else if (col0 < 768) vb[(size_t)row * 256 + (col - 512)] = f2bf(vx);
        else {
          const int cc = col - 768;
          vx += beas[cc];
          vx *= sigmoid_f(vx);
          sesa[(size_t)row * 128 + cc] = vx;
        }
      }
    }
}

// ---------- generic bf16 GEMM (N=256,K=256): C = act(A @ W + bias) ----------
__global__ __launch_bounds__(256) void gemm_bf16_k(
    const ushort* __restrict__ A, const ushort* __restrict__ Wt,
    const float* __restrict__ bias, float* __restrict__ Cf,
    ushort* __restrict__ Cb, int act)
{
  __shared__ ushort As[2][64 * 72];
  __shared__ ushort Ws[2][64 * 72];
  const int tid = threadIdx.x;
  const int wv = tid >> 6, l = tid & 63;
  const int ln = l & 15, hi = l >> 4, hi4 = hi << 2, hi8 = hi << 3;
  const int wr = wv >> 1, wc = wv & 1;
  const int row0 = blockIdx.y * 64, col0 = blockIdx.x * 64;
  const int r_ = tid >> 3, c8_ = (tid & 7) << 3;

  short8_t pA[2], pB[2];
  auto loadT = [&](int k0) {
    pA[0] = *(const short8_t*)&A[(size_t)(row0 + r_) * 256 + k0 + c8_];
    pA[1] = *(const short8_t*)&A[(size_t)(row0 + 32 + r_) * 256 + k0 + c8_];
    pB[0] = *(const short8_t*)&Wt[(size_t)(col0 + r_) * 256 + k0 + c8_];
    pB[1] = *(const short8_t*)&Wt[(size_t)(col0 + 32 + r_) * 256 + k0 + c8_];
  };
  auto commitT = [&](int b) {
    *(short8_t*)&As[b][r_ * 72 + c8_] = pA[0];
    *(short8_t*)&As[b][(32 + r_) * 72 + c8_] = pA[1];
    *(short8_t*)&Ws[b][r_ * 72 + c8_] = pB[0];
    *(short8_t*)&Ws[b][(32 + r_) * 72 + c8_] = pB[1];
  };

  f32x4 acc[2][2];
  #pragma unroll
  for (int i = 0; i < 2; ++i)
    #pragma unroll
    for (int j = 0; j < 2; ++j)
      #pragma unroll
      for (int r = 0; r < 4; ++r) acc[i][j][r] = 0.f;

  loadT(0); commitT(0); __syncthreads();
  #pragma unroll
  for (int t = 0; t < 4; ++t) {
    const int b = t & 1;
    if (t < 3) loadT((t + 1) << 6);
    #pragma unroll
    for (int kk = 0; kk < 2; ++kk) {
      short8_t a0 = *(const short8_t*)&As[b][(wr * 32 + ln) * 72 + kk * 32 + hi8];
      short8_t a1 = *(const short8_t*)&As[b][(wr * 32 + 16 + ln) * 72 + kk * 32 + hi8];
      short8_t b0 = *(const short8_t*)&Ws[b][(wc * 32 + ln) * 72 + kk * 32 + hi8];
      short8_t b1 = *(const short8_t*)&Ws[b][(wc * 32 + 16 + ln) * 72 + kk * 32 + hi8];
      acc[0][0] = __builtin_amdgcn_mfma_f32_16x16x32_bf16(a0, b0, acc[0][0], 0, 0, 0);
      acc[0][1] = __builtin_amdgcn_mfma_f32_16x16x32_bf16(a0, b1, acc[0][1], 0, 0, 0);
      acc[1][0] = __builtin_amdgcn_mfma_f32_16x16x32_bf16(a1, b0, acc[1][0], 0, 0, 0);
      acc[1][1] = __builtin_amdgcn_mfma_f32_16x16x32_bf16(a1, b1, acc[1][1], 0, 0, 0);
    }
    if (t < 3) commitT(b ^ 1);
    __syncthreads();
  }

  #pragma unroll
  for (int mi = 0; mi < 2; ++mi)
    #pragma unroll
    for (int ni = 0; ni < 2; ++ni) {
      const int col = col0 + wc * 32 + ni * 16 + ln;
      const float bval = bias ? bias[col] : 0.f;
      #pragma unroll
      for (int r = 0; r < 4; ++r) {
        const int row = row0 + wr * 32 + mi * 16 + hi4 + r;
        float vx = acc[mi][ni][r] + bval;
        if (act == 1) vx = vx * sigmoid_f(vx);
        if (Cf) Cf[(size_t)row * 256 + col] = vx;
        if (Cb) Cb[(size_t)row * 256 + col] = f2bf(vx);
      }
    }
}

// ---------- fused knorm + etaalpha ----------
__global__ __launch_bounds__(256) void knea_k(
    const float* __restrict__ kf, ushort* __restrict__ kb,
    const float* __restrict__ sesa,
    const float* __restrict__ We2, const float* __restrict__ be2,
    const float* __restrict__ Wa2, const float* __restrict__ ba2,
    float* __restrict__ eta, float* __restrict__ alpha)
{
  const int lane = threadIdx.x & 63;
  const size_t row = ((size_t)blockIdx.x << 2) + (threadIdx.x >> 6);
  {
    const size_t off = row * F_ + ((size_t)lane << 2);
    float4 v = *(const float4*)&kf[off];
    float ss = v.x * v.x + v.y * v.y + v.z * v.z + v.w * v.w;
    #pragma unroll
    for (int m = 1; m < 64; m <<= 1) ss += __shfl_xor(ss, m, 64);
    const float sc = 1.0f / fmaxf(sqrtf(ss), 1e-12f);
    ushort4 o;
    o.x = f2bf(v.x * sc); o.y = f2bf(v.y * sc);
    o.z = f2bf(v.z * sc); o.w = f2bf(v.w * sc);
    *(ushort4*)&kb[off] = o;
  }
  {
    float pe = sesa[row * 128 + lane] * We2[lane];
    float pa = sesa[row * 128 + 64 + lane] * Wa2[lane];
    #pragma unroll
    for (int m = 1; m < 64; m <<= 1) {
      pe += __shfl_xor(pe, m, 64);
      pa += __shfl_xor(pa, m, 64);
    }
    if (lane == 0) {
      eta[row]   = sigmoid_f(pe + be2[0]) * 0.1f + 0.01f;
      alpha[row] = sigmoid_f(pa + ba2[0]) * 0.5f + 0.5f;
    }
  }
}

__global__ __launch_bounds__(256) void ln_k(
    const float* __restrict__ t, const float* __restrict__ x,
    const float* __restrict__ gamma, const float* __restrict__ beta,
    float* __restrict__ y)
{
  const int lane = threadIdx.x & 63;
  const size_t row = ((size_t)blockIdx.x << 2) + (threadIdx.x >> 6);
  const size_t off = row * F_ + ((size_t)lane << 2);
  const float4 tv = *(const float4*)&t[off];
  const float4 xv = *(const float4*)&x[off];
  float4 v = make_float4(tv.x + xv.x, tv.y + xv.y, tv.z + xv.z, tv.w + xv.w);
  float sm = v.x + v.y + v.z + v.w;
  float sq = v.x * v.x + v.y * v.y + v.z * v.z + v.w * v.w;
  #pragma unroll
  for (int m = 1; m < 64; m <<= 1) {
    sm += __shfl_xor(sm, m, 64);
    sq += __shfl_xor(sq, m, 64);
  }
  const float mu  = sm * (1.0f / 256.0f);
  const float var = sq * (1.0f / 256.0f) - mu * mu;
  const float rstd = rsqrtf(var + 1e-5f);
  const float4 g = *(const float4*)&gamma[(size_t)lane << 2];
  const float4 b = *(const float4*)&beta[(size_t)lane << 2];
  float4 o;
  o.x = (v.x - mu) * rstd * g.x + b.x;
  o.y = (v.y - mu) * rstd * g.y + b.y;
  o.z = (v.z - mu) * rstd * g.z + b.z;
  o.w = (v.w - mu) * rstd * g.w + b.w;
  *(float4*)&y[off] = o;
}

// ---- prep: per (chunk, head): G=KK^T, masked Gq=QK^T, decay scalars,
// T = (I + strictlower(diag(b) G))^{-1}, and transposed-K global copy.
__global__ __launch_bounds__(256) void prep_k(
    const ushort* __restrict__ kb, const ushort* __restrict__ qb,
    const float* __restrict__ eta, const float* __restrict__ alpha,
    ushort* __restrict__ Tg, ushort* __restrict__ Gqg, float* __restrict__ Sg,
    ushort* __restrict__ Ktg)
{
  __shared__ ushort K_lds[CCH * KSTR];
  __shared__ ushort Q_lds[CCH * KSTR];
  __shared__ float  G_lds[CCH * CCH];
  __shared__ float  ea[2 * CCH];
  __shared__ float  scal[100];

  const int tid = threadIdx.x;
  const int ch = blockIdx.x, h = blockIdx.y;
  const int t0 = ch * CCH;
  const int l = tid & 63, wv = tid >> 6;
  const int ln = l & 15, hi = l >> 4;
  const int hi8 = hi * 8, hi4 = hi * 4;

  const ushort* kg = kb + (size_t)(h * S_ + t0) * F_;
  const ushort* qg = qb + (size_t)(h * S_ + t0) * F_;
  #pragma unroll
  for (int w = 0; w < 4; ++w) {
    int o = w * 256 + tid; int t = o >> 5, c8 = (o & 31) << 3;
    *(short8_t*)&K_lds[t * KSTR + c8] = *(const short8_t*)&kg[(size_t)t * F_ + c8];
    *(short8_t*)&Q_lds[t * KSTR + c8] = *(const short8_t*)&qg[(size_t)t * F_ + c8];
  }
  if (tid < CCH)            ea[tid] = eta[(size_t)h * S_ + t0 + tid];
  else if (tid < 2 * CCH)   ea[tid] = alpha[(size_t)h * S_ + t0 + tid - CCH];
  __syncthreads();

  // transposed K copy: Ktg[h][c][t]
  {
    const int tt = tid & 31, cl = tid >> 5;
    for (int cp = 0; cp < 32; ++cp) {
      const int c = cp * 8 + cl;
      Ktg[((size_t)h * F_ + c) * S_ + t0 + tt] = K_lds[tt * KSTR + c];
    }
  }

  {
    const int tI = wv >> 1, tJ = wv & 1;
    f32x4 accG = {0.f, 0.f, 0.f, 0.f};
    f32x4 accQ = {0.f, 0.f, 0.f, 0.f};
    #pragma unroll
    for (int ko = 0; ko < 8; ++ko) {
      const int cb = ko * 32 + hi8;
      short8_t bfr = *(const short8_t*)&K_lds[(tJ * 16 + ln) * KSTR + cb];
      short8_t aK  = *(const short8_t*)&K_lds[(tI * 16 + ln) * KSTR + cb];
      short8_t aQ  = *(const short8_t*)&Q_lds[(tI * 16 + ln) * KSTR + cb];
      accG = __builtin_amdgcn_mfma_f32_16x16x32_bf16(aK, bfr, accG, 0, 0, 0);
      accQ = __builtin_amdgcn_mfma_f32_16x16x32_bf16(aQ, bfr, accQ, 0, 0, 0);
    }
    ushort* Gqo = Gqg + (size_t)(h * NCH + ch) * (CCH * CCH);
    #pragma unroll
    for (int r = 0; r < 4; ++r) {
      const int t = tI * 16 + hi4 + r, s = tJ * 16 + ln;
      G_lds[t * CCH + s] = accG[r];
      Gqo[t * CCH + s] = (s < t) ? f2bf(accQ[r]) : (ushort)0;
    }
  }
  if (tid == 0) {
    float gp = 1.f;
    for (int t = 0; t < CCH; ++t) {
      const float a = ea[CCH + t], e = ea[t];
      const float gm = gp * a;
      scal[t]           = e / a;    // b_t
      scal[CCH + t]     = e / gm;   // c_t
      scal[2 * CCH + t] = gp;       // gamma_prev
      gp = gm;
    }
    scal[3 * CCH] = gp;             // gamma_C
  }
  __syncthreads();

  // forward substitution: column j of T
  {
    const int j = tid >> 3, g = tid & 7;
    float x0 = 0.f, x1 = 0.f, x2 = 0.f, x3 = 0.f;
    ushort* To = Tg + (size_t)(h * NCH + ch) * (CCH * CCH);
    #pragma unroll
    for (int t = 0; t < CCH; ++t) {
      float p = 0.f;
      const f32x4 gr = *(const f32x4*)&G_lds[t * CCH + 4 * g];
      if (4 * g + 0 < t) p += gr[0] * x0;
      if (4 * g + 1 < t) p += gr[1] * x1;
      if (4 * g + 2 < t) p += gr[2] * x2;
      if (4 * g + 3 < t) p += gr[3] * x3;
      const float tot = red8(p);
      const float xt = ((t == j) ? 1.f : 0.f) - scal[t] * tot;
      if (g == (t >> 2)) {
        if ((t & 3) == 0) x0 = xt; else if ((t & 3) == 1) x1 = xt;
        else if ((t & 3) == 2) x2 = xt; else x3 = xt;
      }
      if (g == 0) To[t * CCH + j] = f2bf(xt);
    }
  }
  if (tid < 97) Sg[(size_t)(h * NCH + ch) * 128 + tid] = scal[tid];
}

// ---- chunked scan v2: K-split KM, wave0 serial middle, concurrent QM,
// double-buffered M, 3 barriers/chunk. Grid 256 blocks (XCD-remapped), 256 thr.
__global__ __launch_bounds__(256, 1) void scan_chunk_k(
    const ushort* __restrict__ kb, const ushort* __restrict__ qb,
    const ushort* __restrict__ vhb, const ushort* __restrict__ Ktg,
    const ushort* __restrict__ Tg, const ushort* __restrict__ Gqg,
    const float* __restrict__ Sg,
    ushort* __restrict__ outb, float* __restrict__ Mout)
{
  __shared__ ushort K_lds[CCH * KSTR];          // 16.9KB
  __shared__ ushort Q_lds[CCH * KSTR];          // 16.9KB
  __shared__ ushort Kt_lds[2][F_ * KTSTR];      // 36.9KB
  __shared__ ushort M_lds[2][16 * KSTR];        // 16.9KB
  __shared__ ushort T_lds[CCH * TSTR];          // 2.6KB
  __shared__ ushort Gq_lds[2][CCH * TSTR];      // 5.1KB
  __shared__ ushort Wt_lds[16 * TSTR];          // 1.3KB
  __shared__ ushort R_lds[16 * TSTR];           // 1.3KB
  __shared__ float  KMp[4 * CCH * PSTR];        // 8.7KB
  __shared__ float  QM_lds[CCH * PSTR];         // 2.2KB
  __shared__ ushort V_lds[CCH * 16];            // 1KB
  __shared__ float  scal[2][104];               // 0.8KB

  const int tid = threadIdx.x;
  const int flat = blockIdx.x;
  const int h = (flat & 7) + ((flat >> 7) << 3);   // XCD-aware remap
  const int slice = (flat >> 3) & 15;
  const int r0 = slice * 16;
  const int wv = tid >> 6, l = tid & 63;
  const int ln = l & 15, hi = l >> 4, hi4 = hi << 2, hi8 = hi << 3;

  for (int u = tid; u < 16 * KSTR / 8; u += 256) {
    short8_t z = {0, 0, 0, 0, 0, 0, 0, 0};
    *(short8_t*)&M_lds[0][u * 8] = z;
  }
  f32x4 Mf[4];
  #pragma unroll
  for (int q = 0; q < 4; ++q)
    #pragma unroll
    for (int r = 0; r < 4; ++r) Mf[q][r] = 0.f;

  const ushort* kgh = kb + (size_t)h * S_ * F_;
  const ushort* qgh = qb + (size_t)h * S_ * F_;
  const ushort* kth = Ktg + (size_t)h * F_ * S_;

  short8_t pK[4], pQ[4], pKt[4], pTG;
  ushort pV[2]; float pS = 0.f;

  auto loadchunk = [&](int ch) {
    const int t0 = ch * CCH;
    #pragma unroll
    for (int r = 0; r < 4; ++r) {
      const int idx = (r << 8) + tid;
      const int t = idx >> 5, c8 = (idx & 31) << 3;
      pK[r] = *(const short8_t*)&kgh[(size_t)(t0 + t) * F_ + c8];
      pQ[r] = *(const short8_t*)&qgh[(size_t)(t0 + t) * F_ + c8];
    }
    #pragma unroll
    for (int r = 0; r < 4; ++r) {
      const int idx = (r << 8) + tid;
      const int c = idx >> 2, t8 = (idx & 3) << 3;
      pKt[r] = *(const short8_t*)&kth[(size_t)c * S_ + t0 + t8];
    }
    #pragma unroll
    for (int u = 0; u < 2; ++u) {
      const int e = (u << 8) + tid, t = e >> 4, i = e & 15;
      pV[u] = vhb[(size_t)(h * S_ + t0 + t) * F_ + r0 + i];
    }
    {
      const ushort* Ti = Tg  + (size_t)(h * NCH + ch) * (CCH * CCH);
      const ushort* Gi = Gqg + (size_t)(h * NCH + ch) * (CCH * CCH);
      if (tid < 128) {
        const int t = tid >> 2, c8 = (tid & 3) << 3;
        pTG = *(const short8_t*)&Ti[t * CCH + c8];
      } else {
        const int t = (tid - 128) >> 2, c8 = ((tid - 128) & 3) << 3;
        pTG = *(const short8_t*)&Gi[t * CCH + c8];
      }
    }
    if (tid < 97) pS = Sg[(size_t)(h * NCH + ch) * 128 + tid];
  };

  auto commit = [&](int b) {
    #pragma unroll
    for (int r = 0; r < 4; ++r) {
      const int idx = (r << 8) + tid;
      const int t = idx >> 5, c8 = (idx & 31) << 3;
      *(short8_t*)&K_lds[t * KSTR + c8] = pK[r];
      *(short8_t*)&Q_lds[t * KSTR + c8] = pQ[r];
    }
    #pragma unroll
    for (int r = 0; r < 4; ++r) {
      const int idx = (r << 8) + tid;
      const int c = idx >> 2, t8 = (idx & 3) << 3;
      *(short8_t*)&Kt_lds[b][c * KTSTR + t8] = pKt[r];
    }
    #pragma unroll
    for (int u = 0; u < 2; ++u) V_lds[(u << 8) + tid] = pV[u];
    if (tid < 128) {
      const int t = tid >> 2, c8 = (tid & 3) << 3;
      *(short8_t*)&T_lds[t * TSTR + c8] = pTG;
    } else {
      const int t = (tid - 128) >> 2, c8 = ((tid - 128) & 3) << 3;
      *(short8_t*)&Gq_lds[b][t * TSTR + c8] = pTG;
    }
    if (tid < 97) scal[b][tid] = pS;
  };

  loadchunk(0);
  commit(0);
  __syncthreads();
  int cb = 0;

  for (int ch = 0; ch < NCH; ++ch) {
    const int t0 = ch * CCH;
    const int nb = cb ^ 1;
    if (ch + 1 < NCH) loadchunk(ch + 1);

    // ---- P1: KM partials, K-split over 4 waves ----
    {
      const int j0 = wv * 64;
      f32x4 a0v = {0.f, 0.f, 0.f, 0.f};
      f32x4 a1v = {0.f, 0.f, 0.f, 0.f};
      #pragma unroll
      for (int ks = 0; ks < 2; ++ks) {
        const int jc = j0 + ks * 32 + hi8;
        short8_t bm = *(const short8_t*)&M_lds[cb][ln * KSTR + jc];
        short8_t a0 = *(const short8_t*)&K_lds[ln * KSTR + jc];
        short8_t a1 = *(const short8_t*)&K_lds[(16 + ln) * KSTR + jc];
        a0v = __builtin_amdgcn_mfma_f32_16x16x32_bf16(a0, bm, a0v, 0, 0, 0);
        a1v = __builtin_amdgcn_mfma_f32_16x16x32_bf16(a1, bm, a1v, 0, 0, 0);
      }
      #pragma unroll
      for (int r = 0; r < 4; ++r) {
        KMp[wv * (CCH * PSTR) + (hi4 + r) * PSTR + ln] = a0v[r];
        KMp[wv * (CCH * PSTR) + (16 + hi4 + r) * PSTR + ln] = a1v[r];
      }
    }
    __syncthreads();

    // ---- P2: wave0 = reduce->RHS->W ; waves 2,3 = QM ----
    if (wv == 0) {
      const int i = l & 15, tg = l >> 4;
      short8_t rv;
      #pragma unroll
      for (int u = 0; u < 8; ++u) {
        const int t = tg * 8 + u;
        const float s = KMp[t * PSTR + i]
                      + KMp[CCH * PSTR + t * PSTR + i]
                      + KMp[2 * CCH * PSTR + t * PSTR + i]
                      + KMp[3 * CCH * PSTR + t * PSTR + i];
        const float rhs = scal[cb][CCH + t] * bf2f(V_lds[t * 16 + i])
                        - scal[cb][t] * s;
        rv[u] = (short)f2bf(rhs);
      }
      *(short8_t*)&R_lds[i * TSTR + tg * 8] = rv;
      #pragma unroll
      for (int I = 0; I < 2; ++I) {
        short8_t a = *(const short8_t*)&T_lds[(I * 16 + ln) * TSTR + hi8];
        short8_t b = *(const short8_t*)&R_lds[ln * TSTR + hi8];
        f32x4 z = {0.f, 0.f, 0.f, 0.f};
        f32x4 d = __builtin_amdgcn_mfma_f32_16x16x32_bf16(a, b, z, 0, 0, 0);
        ushort4 wo;
        wo.x = f2bf(d[0]); wo.y = f2bf(d[1]); wo.z = f2bf(d[2]); wo.w = f2bf(d[3]);
        *(ushort4*)&Wt_lds[ln * TSTR + I * 16 + hi4] = wo;
      }
    } else if (wv >= 2) {
      const int I = wv - 2;
      f32x4 acc = {0.f, 0.f, 0.f, 0.f};
      #pragma unroll
      for (int ko = 0; ko < 8; ++ko) {
        short8_t a = *(const short8_t*)&Q_lds[(I * 16 + ln) * KSTR + ko * 32 + hi8];
        short8_t b = *(const short8_t*)&M_lds[cb][ln * KSTR + ko * 32 + hi8];
        acc = __builtin_amdgcn_mfma_f32_16x16x32_bf16(a, b, acc, 0, 0, 0);
      }
      #pragma unroll
      for (int r = 0; r < 4; ++r)
        QM_lds[(I * 16 + hi4 + r) * PSTR + ln] = acc[r];
    }
    __syncthreads();

    // ---- P3: M-update (all) + OUT (waves 0,1) + commit next ----
    {
      const float gC = scal[cb][3 * CCH];
      short8_t aw = *(const short8_t*)&Wt_lds[ln * TSTR + hi8];
      #pragma unroll
      for (int qq = 0; qq < 4; ++qq) {
        const int jt = wv * 4 + qq;
        short8_t bk = *(const short8_t*)&Kt_lds[cb][(jt * 16 + ln) * KTSTR + hi8];
        f32x4 d = __builtin_amdgcn_mfma_f32_16x16x32_bf16(aw, bk, Mf[qq], 0, 0, 0);
        #pragma unroll
        for (int r = 0; r < 4; ++r) {
          const float nv = gC * d[r];
          Mf[qq][r] = nv;
          M_lds[nb][(hi4 + r) * KSTR + jt * 16 + ln] = f2bf(nv);
        }
      }
    }
    if (wv < 2) {
      const int I = wv;
      short8_t a = *(const short8_t*)&Gq_lds[cb][(I * 16 + ln) * TSTR + hi8];
      short8_t b = *(const short8_t*)&Wt_lds[ln * TSTR + hi8];
      f32x4 z = {0.f, 0.f, 0.f, 0.f};
      f32x4 d = __builtin_amdgcn_mfma_f32_16x16x32_bf16(a, b, z, 0, 0, 0);
      #pragma unroll
      for (int r = 0; r < 4; ++r) {
        const int t = I * 16 + hi4 + r;
        const float ov = scal[cb][2 * CCH + t] * (QM_lds[t * PSTR + ln] + d[r]);
        outb[(size_t)(h * S_ + t0 + t) * F_ + r0 + ln] = f2bf(ov);
      }
    }
    if (ch + 1 < NCH) commit(nb);
    __syncthreads();
    cb = nb;
  }

  #pragma unroll
  for (int qq = 0; qq < 4; ++qq) {
    const int jt = wv * 4 + qq;
    #pragma unroll
    for (int r = 0; r < 4; ++r)
      Mout[((size_t)h * F_ + r0 + hi4 + r) * F_ + jt * 16 + ln] = Mf[qq][r];
  }
}

extern "C" void kernel_launch(void* const* d_in, const int* in_sizes, int n_in,
                              void* d_out, int out_size, void* d_ws, size_t ws_size,
                              hipStream_t stream)
{
  const float* x    = (const float*)d_in[0];
  const float* Wq   = (const float*)d_in[1];
  const float* Wk   = (const float*)d_in[2];
  const float* Wv   = (const float*)d_in[3];
  const float* Wg1  = (const float*)d_in[4];
  const float* bg1  = (const float*)d_in[5];
  const float* Wg2  = (const float*)d_in[6];
  const float* bg2  = (const float*)d_in[7];
  const float* We1  = (const float*)d_in[8];
  const float* be1  = (const float*)d_in[9];
  const float* We2  = (const float*)d_in[10];
  const float* be2  = (const float*)d_in[11];
  const float* Wa1  = (const float*)d_in[12];
  const float* ba1  = (const float*)d_in[13];
  const float* Wa2  = (const float*)d_in[14];
  const float* ba2  = (const float*)d_in[15];
  const float* Wo   = (const float*)d_in[16];
  const float* bo   = (const float*)d_in[17];
  const float* gamma= (const float*)d_in[18];
  const float* beta = (const float*)d_in[19];

  const int Mrows = NH_ * S_;               // 8192
  const size_t MM = 1048576;                // 1M floats
  const size_t NTF = 2 * MM;

  float* ws = (float*)d_ws;
  // f32-offset layout (aggressive reuse):
  ushort* xb   = (ushort*)(ws + 0 * MM);   // bf16 x; dead after qkve
  ushort* outb = (ushort*)(ws + 0 * MM);   // reuse: scan output
  ushort* qb   = (ushort*)(ws + 1 * MM);
  ushort* kb   = (ushort*)(ws + 2 * MM);
  float*  kf   = ws + 3 * MM;              // f32 [3M,5M); dead after knea
  ushort* t1b  = (ushort*)(ws + 3 * MM);   // reuse after knea
  ushort* vhb  = (ushort*)(ws + 4 * MM);   // bf16 v_hat
  ushort* vb   = (ushort*)(ws + 5 * MM);   // bf16 v; dead after t1 gemm
  float*  sesa = ws + 6 * MM;              // f32 [6M,7M); dead after knea
  float*  ytmp = ws + 5 * MM;              // f32 [5M,7M); after scan
  float*  eta  = ws + 7 * MM;
  float*  alpha= eta + Mrows;
  ushort* Tg   = (ushort*)(ws + 7 * MM + 16384);
  ushort* Gqg  = Tg + 262144;
  float*  Sg   = ws + 7 * MM + 16384 + 131072 + 131072;
  ushort* Ktg  = (ushort*)(Sg + 32768);
  ushort* Wt   = Ktg + 2097152;
  float*  beas = (float*)(Wt + 425984);

  dim3 blk(256);

  wconv_k<<<233, blk, 0, stream>>>(Wq, Wk, Wv, Wg1, Wg2, Wo, We1, Wa1,
                                   be1, ba1, x, Wt, beas, xb);

  qkve_k<<<dim3(14, 128), blk, 0, stream>>>(xb, Wt, beas, qb, kf, vb, sesa);

  knea_k<<<Mrows / 4, blk, 0, stream>>>(kf, kb, sesa, We2, be2, Wa2, ba2, eta, alpha);

  gemm_bf16_k<<<dim3(4, 128), blk, 0, stream>>>(vb,  Wt + 229376, bg1, nullptr, t1b, 1);
  gemm_bf16_k<<<dim3(4, 128), blk, 0, stream>>>(t1b, Wt + 294912, bg2, nullptr, vhb, 0);

  prep_k<<<dim3(NCH, NH_), blk, 0, stream>>>(kb, qb, eta, alpha, Tg, Gqg, Sg, Ktg);

  float* yout = (float*)d_out;
  float* Mfin = yout + NTF;
  scan_chunk_k<<<256, blk, 0, stream>>>(kb, qb, vhb, Ktg, Tg, Gqg, Sg, outb, Mfin);

  gemm_bf16_k<<<dim3(4, 128), blk, 0, stream>>>(outb, Wt + 360448, bo, ytmp, nullptr, 0);
  ln_k<<<Mrows / 4, blk, 0, stream>>>(ytmp, x, gamma, beta, yout);
}